// Round 1
// baseline (599.595 us; speedup 1.0000x reference)
//
#include <hip/hip_runtime.h>
#include <math.h>

#define B_  2
#define L_  1024
#define D_  1024
#define H_  16
#define HD_ 64

// ---------------------------------------------------------------------------
// GEMM: out = A @ W^T + bias.  A:[M,K] row-major, W:[N,K] row-major (so both
// stream the K dim contiguously).  HEAD_LAYOUT=true writes [B,H,L,hd] layout.
// BM=BN=64, BK=16, 256 threads, 4x4 per thread.
// ---------------------------------------------------------------------------
template<bool HEAD_LAYOUT>
__global__ __launch_bounds__(256)
void gemm_bt(const float* __restrict__ A, const float* __restrict__ W,
             const float* __restrict__ bias, float* __restrict__ out,
             int M, int N, int Kd) {
    const int t  = threadIdx.x;
    const int tx = t & 15, ty = t >> 4;
    const int m0 = blockIdx.y << 6, n0 = blockIdx.x << 6;

    __shared__ float As[16][68];  // [k][m], pad 68 for 16B-aligned float4 rows
    __shared__ float Bs[16][68];  // [k][n]

    float acc[4][4] = {};

    const int lr = t >> 2;         // 0..63 tile row
    const int lc = (t & 3) << 2;   // 0,4,8,12 k offset

    for (int k0 = 0; k0 < Kd; k0 += 16) {
        __syncthreads();
        float4 av = *(const float4*)&A[(size_t)(m0 + lr) * Kd + k0 + lc];
        float4 bv = *(const float4*)&W[(size_t)(n0 + lr) * Kd + k0 + lc];
        As[lc + 0][lr] = av.x; As[lc + 1][lr] = av.y;
        As[lc + 2][lr] = av.z; As[lc + 3][lr] = av.w;
        Bs[lc + 0][lr] = bv.x; Bs[lc + 1][lr] = bv.y;
        Bs[lc + 2][lr] = bv.z; Bs[lc + 3][lr] = bv.w;
        __syncthreads();
#pragma unroll
        for (int k = 0; k < 16; ++k) {
            float4 a4 = *(const float4*)&As[k][ty << 2];
            float4 b4 = *(const float4*)&Bs[k][tx << 2];
            float af[4] = {a4.x, a4.y, a4.z, a4.w};
            float bf[4] = {b4.x, b4.y, b4.z, b4.w};
#pragma unroll
            for (int i = 0; i < 4; ++i)
#pragma unroll
                for (int j = 0; j < 4; ++j)
                    acc[i][j] += af[i] * bf[j];
        }
    }

#pragma unroll
    for (int i = 0; i < 4; ++i) {
        const int m = m0 + (ty << 2) + i;
#pragma unroll
        for (int j = 0; j < 4; ++j) {
            const int n = n0 + (tx << 2) + j;
            const float v = acc[i][j] + bias[n];
            if (HEAD_LAYOUT) {
                const int b = m >> 10, l = m & 1023;
                const int h = n >> 6,  d = n & 63;
                out[((((size_t)b * H_ + h) * L_ + l) << 6) + d] = v;
            } else {
                out[(size_t)m * N + n] = v;
            }
        }
    }
}

// ---------------------------------------------------------------------------
// Row norms: qn[b,h,l] = sum_d Q^2, kn likewise.  One 64-thread block per row.
// ---------------------------------------------------------------------------
__global__ void norms_kernel(const float* __restrict__ Q,
                             const float* __restrict__ K,
                             float* __restrict__ qn, float* __restrict__ kn) {
    const int NR = B_ * H_ * L_;
    int row = blockIdx.x;
    const float* src = (row < NR) ? Q : K;
    float* dst = (row < NR) ? qn : kn;
    if (row >= NR) row -= NR;
    float v = src[(size_t)row * HD_ + threadIdx.x];
    v *= v;
#pragma unroll
    for (int off = 32; off; off >>= 1) v += __shfl_down(v, off);
    if (threadIdx.x == 0) dst[row] = v;
}

// ---------------------------------------------------------------------------
// Kuramoto step (tiny): phases, order -> d_out tail; phase_mod -> ws
// ---------------------------------------------------------------------------
__global__ void kuramoto_kernel(const float* __restrict__ omega,
                                const float* __restrict__ theta0,
                                const float* __restrict__ cK,
                                float* __restrict__ out_tail,  // d_out + B*L*D
                                float* __restrict__ phase_mod) {
    __shared__ float ph[H_];
    __shared__ float mc_s, ms_s;
    const int i = threadIdx.x;
    if (i < H_) {
        const float ti = theta0[i];
        float s = 0.f;
        for (int j = 0; j < H_; ++j) s += cK[i * H_ + j] * sinf(theta0[j] - ti);
        ph[i] = ti + 0.1f * (omega[i] + (1.0f / H_) * s);
    }
    __syncthreads();
    if (i == 0) {
        float mc = 0.f, ms = 0.f;
        for (int j = 0; j < H_; ++j) { mc += cosf(ph[j]); ms += sinf(ph[j]); }
        mc *= (1.0f / H_); ms *= (1.0f / H_);
        mc_s = mc; ms_s = ms;
        const float ord = sqrtf(mc * mc + ms * ms);
        out_tail[B_ * H_ + 0] = ord;   // order[b=0]
        out_tail[B_ * H_ + 1] = ord;   // order[b=1]
    }
    __syncthreads();
    if (i < H_) {
        const float p = ph[i];
        const float pmv = cosf(p) * mc_s + sinf(p) * ms_s;
        out_tail[i] = p;          // phases[0,i]
        out_tail[H_ + i] = p;     // phases[1,i]
        phase_mod[i] = pmv;
        phase_mod[H_ + i] = pmv;
    }
}

// ---------------------------------------------------------------------------
// Fused hyperbolic attention, flash-style online softmax.
// Grid: (L/64 l-tiles, B*H).  Block 256 = 16x16, 4x4 scores per thread.
// score = phase_mod / (arg + sqrt(max(arg^2-1, 1e-8)))   [== exp(-dist)*pm]
// ---------------------------------------------------------------------------
__global__ __launch_bounds__(256)
void attn_kernel(const float* __restrict__ Q, const float* __restrict__ K,
                 const float* __restrict__ V, const float* __restrict__ qn,
                 const float* __restrict__ kn, const float* __restrict__ pm_arr,
                 const int* __restrict__ mask, float* __restrict__ ctx) {
    const int bh = blockIdx.y;           // b*H + h
    const int b  = bh >> 4, h = bh & 15;
    const int l0 = blockIdx.x << 6;
    const int t  = threadIdx.x;
    const int tx = t & 15, ty = t >> 4;

    __shared__ float Qs[64][68];    // [l][d]
    __shared__ float Kst[64][68];   // [d][s]   (transposed)
    __shared__ float Vs[64][68];    // [s][d]
    __shared__ float Ps[64][68];    // [l][s]
    __shared__ float qn_sh[64], kn_sh[64];

    const float pm = pm_arr[bh];
    const size_t base = (size_t)bh * L_ * HD_;

    {   // load Q tile (coalesced float4 per row)
        const int r  = t >> 4;
        const int c4 = (t & 15) << 2;
        for (int rr = 0; rr < 64; rr += 16) {
            float4 v = *(const float4*)&Q[base + (size_t)(l0 + rr + r) * HD_ + c4];
            *(float4*)&Qs[rr + r][c4] = v;
        }
    }
    if (t < 64) qn_sh[t] = qn[bh * L_ + l0 + t];

    float m_run[4], l_run[4], cacc[4][4];
#pragma unroll
    for (int i = 0; i < 4; ++i) {
        m_run[i] = -INFINITY; l_run[i] = 0.f;
#pragma unroll
        for (int j = 0; j < 4; ++j) cacc[i][j] = 0.f;
    }

    for (int s0 = 0; s0 < L_; s0 += 64) {
        __syncthreads();
        {   // load K (transposed into Kst) and V tiles
            const int r  = t >> 4;
            const int c4 = (t & 15) << 2;
            for (int rr = 0; rr < 64; rr += 16) {
                const int s = rr + r;
                float4 kv = *(const float4*)&K[base + (size_t)(s0 + s) * HD_ + c4];
                Kst[c4 + 0][s] = kv.x; Kst[c4 + 1][s] = kv.y;
                Kst[c4 + 2][s] = kv.z; Kst[c4 + 3][s] = kv.w;
                float4 vv = *(const float4*)&V[base + (size_t)(s0 + s) * HD_ + c4];
                *(float4*)&Vs[s][c4] = vv;
            }
            if (t < 64) kn_sh[t] = kn[bh * L_ + s0 + t];
        }
        __syncthreads();

        // ---- QK^T micro-tile ----
        float dot[4][4] = {};
#pragma unroll
        for (int d4 = 0; d4 < 64; d4 += 4) {
            float a[4][4], bb[4][4];
#pragma unroll
            for (int i = 0; i < 4; ++i) {
                float4 v = *(const float4*)&Qs[(ty << 2) + i][d4];
                a[i][0] = v.x; a[i][1] = v.y; a[i][2] = v.z; a[i][3] = v.w;
            }
#pragma unroll
            for (int k = 0; k < 4; ++k) {
                float4 v = *(const float4*)&Kst[d4 + k][tx << 2];
                bb[k][0] = v.x; bb[k][1] = v.y; bb[k][2] = v.z; bb[k][3] = v.w;
            }
#pragma unroll
            for (int i = 0; i < 4; ++i)
#pragma unroll
                for (int j = 0; j < 4; ++j)
#pragma unroll
                    for (int k = 0; k < 4; ++k)
                        dot[i][j] += a[i][k] * bb[k][j];
        }

        // ---- score transform + mask ----
        float sc[4][4];
#pragma unroll
        for (int i = 0; i < 4; ++i) {
            const float qv = qn_sh[(ty << 2) + i];
            const float qc = fminf(qv, 0.99f);
            const int   l  = l0 + (ty << 2) + i;
#pragma unroll
            for (int j = 0; j < 4; ++j) {
                const float kv = kn_sh[(tx << 2) + j];
                const float kc = fminf(kv, 0.99f);
                const float diff  = fmaxf(qv + kv - 2.f * dot[i][j], 0.f);
                const float denom = (1.f - qc) * (1.f - kc);
                const float arg   = 1.f + 2.f * diff / (denom + 1e-8f);
                const float z     = arg + sqrtf(fmaxf(arg * arg - 1.f, 1e-8f));
                float s = pm / z;   // == exp(-dist) * phase_mod
                const int mk = mask[(size_t)b * L_ * L_ + (size_t)l * L_ + s0 + (tx << 2) + j];
                sc[i][j] = mk ? s : -1e30f;
            }
        }

        // ---- online softmax update (row groups = 16 lanes sharing ty) ----
#pragma unroll
        for (int i = 0; i < 4; ++i) {
            float tmax = sc[i][0];
#pragma unroll
            for (int j = 1; j < 4; ++j) tmax = fmaxf(tmax, sc[i][j]);
#pragma unroll
            for (int off = 1; off < 16; off <<= 1)
                tmax = fmaxf(tmax, __shfl_xor(tmax, off));
            const float mnew  = fmaxf(m_run[i], tmax);
            const float scale = __expf(m_run[i] - mnew);
            float psum = 0.f;
#pragma unroll
            for (int j = 0; j < 4; ++j) {
                const float p = __expf(sc[i][j] - mnew);
                Ps[(ty << 2) + i][(tx << 2) + j] = p;
                psum += p;
            }
#pragma unroll
            for (int off = 1; off < 16; off <<= 1)
                psum += __shfl_xor(psum, off);
            l_run[i] = l_run[i] * scale + psum;
            m_run[i] = mnew;
#pragma unroll
            for (int j = 0; j < 4; ++j) cacc[i][j] *= scale;
        }
        __syncthreads();

        // ---- PV micro-tile ----
#pragma unroll
        for (int s4 = 0; s4 < 64; s4 += 4) {
            float pa[4][4], vv[4][4];
#pragma unroll
            for (int i = 0; i < 4; ++i) {
                float4 v = *(const float4*)&Ps[(ty << 2) + i][s4];
                pa[i][0] = v.x; pa[i][1] = v.y; pa[i][2] = v.z; pa[i][3] = v.w;
            }
#pragma unroll
            for (int k = 0; k < 4; ++k) {
                float4 v = *(const float4*)&Vs[s4 + k][tx << 2];
                vv[k][0] = v.x; vv[k][1] = v.y; vv[k][2] = v.z; vv[k][3] = v.w;
            }
#pragma unroll
            for (int i = 0; i < 4; ++i)
#pragma unroll
                for (int j = 0; j < 4; ++j)
#pragma unroll
                    for (int k = 0; k < 4; ++k)
                        cacc[i][j] += pa[i][k] * vv[k][j];
        }
    }

    // ---- write ctx in [B, L, D] layout ----
#pragma unroll
    for (int i = 0; i < 4; ++i) {
        const int l = l0 + (ty << 2) + i;
        const float inv = 1.f / l_run[i];
        float4 o;
        o.x = cacc[i][0] * inv; o.y = cacc[i][1] * inv;
        o.z = cacc[i][2] * inv; o.w = cacc[i][3] * inv;
        *(float4*)&ctx[((size_t)b * L_ + l) * D_ + (h << 6) + (tx << 2)] = o;
    }
}

// ---------------------------------------------------------------------------
extern "C" void kernel_launch(void* const* d_in, const int* in_sizes, int n_in,
                              void* d_out, int out_size, void* d_ws, size_t ws_size,
                              hipStream_t stream) {
    const float* hs     = (const float*)d_in[0];
    const int*   mask   = (const int*)  d_in[1];
    const float* Wq     = (const float*)d_in[2];
    const float* bq     = (const float*)d_in[3];
    const float* Wk     = (const float*)d_in[4];
    const float* bk     = (const float*)d_in[5];
    const float* Wv     = (const float*)d_in[6];
    const float* bv     = (const float*)d_in[7];
    const float* Wo     = (const float*)d_in[8];
    const float* bo     = (const float*)d_in[9];
    const float* omega  = (const float*)d_in[10];
    const float* theta0 = (const float*)d_in[11];
    const float* cK     = (const float*)d_in[12];
    float* out = (float*)d_out;

    float* ws  = (float*)d_ws;
    const size_t NQKV = (size_t)B_ * H_ * L_ * HD_;   // 2M floats each
    float* Q   = ws;
    float* K   = Q + NQKV;
    float* V   = K + NQKV;
    float* qn  = V + NQKV;
    float* kn  = qn + (size_t)B_ * H_ * L_;
    float* pm  = kn + (size_t)B_ * H_ * L_;
    float* ctx = pm + 64;

    const dim3 ggrid(D_ / 64, (B_ * L_) / 64);   // (16, 32)

    gemm_bt<true><<<ggrid, 256, 0, stream>>>(hs, Wq, bq, Q, B_ * L_, D_, D_);
    gemm_bt<true><<<ggrid, 256, 0, stream>>>(hs, Wk, bk, K, B_ * L_, D_, D_);
    gemm_bt<true><<<ggrid, 256, 0, stream>>>(hs, Wv, bv, V, B_ * L_, D_, D_);

    norms_kernel<<<2 * B_ * H_ * L_, 64, 0, stream>>>(Q, K, qn, kn);

    kuramoto_kernel<<<1, 64, 0, stream>>>(omega, theta0, cK,
                                          out + (size_t)B_ * L_ * D_, pm);

    attn_kernel<<<dim3(L_ / 64, B_ * H_), 256, 0, stream>>>(Q, K, V, qn, kn,
                                                            pm, mask, ctx);

    gemm_bt<false><<<ggrid, 256, 0, stream>>>(ctx, Wo, bo, out, B_ * L_, D_, D_);
}

// Round 2
// 243.507 us; speedup vs baseline: 2.4623x; 2.4623x over previous
//
#include <hip/hip_runtime.h>
#include <hip/hip_bf16.h>
#include <math.h>

#define B_  2
#define L_  1024
#define D_  1024
#define H_  16
#define HD_ 64

typedef __attribute__((ext_vector_type(8))) short short8;
typedef __attribute__((ext_vector_type(4))) float f32x4;
typedef unsigned int u32;
typedef unsigned long long u64;

__device__ inline float b2f(short s) {
    union { float f; u32 i; } c; c.i = ((u32)(unsigned short)s) << 16; return c.f;
}
__device__ inline unsigned short f2b(float f) {
    __hip_bfloat16 h = __float2bfloat16(f);
    return *reinterpret_cast<unsigned short*>(&h);
}
__device__ inline void gld_lds16(const void* g, void* l) {
    __builtin_amdgcn_global_load_lds((const __attribute__((address_space(1))) u32*)g,
                                     (__attribute__((address_space(3))) u32*)l, 16, 0, 0);
}

// ---------------------------------------------------------------------------
// fp32 -> bf16 cast, 4 elems/thread
// ---------------------------------------------------------------------------
__global__ void cast4_kernel(const float* __restrict__ in,
                             unsigned short* __restrict__ out, int n4) {
    const int i = blockIdx.x * 256 + threadIdx.x;
    if (i < n4) {
        float4 v = ((const float4*)in)[i];
        ushort4 o;
        o.x = f2b(v.x); o.y = f2b(v.y); o.z = f2b(v.z); o.w = f2b(v.w);
        ((ushort4*)out)[i] = o;
    }
}

// ---------------------------------------------------------------------------
// mask [B,1,L,L] int -> bitmask u64 per 64 s-cols
// ---------------------------------------------------------------------------
__global__ void pack_mask_kernel(const int* __restrict__ mask,
                                 u64* __restrict__ bits, int n) {
    const int i = blockIdx.x * 256 + threadIdx.x;
    const int v = (i < n) ? mask[i] : 1;
    const u64 bal = __ballot(v != 0);
    if ((threadIdx.x & 63) == 0 && i < n) bits[i >> 6] = bal;
}

// ---------------------------------------------------------------------------
// Kuramoto step (tiny): phases, order -> d_out tail; phase_mod -> ws
// ---------------------------------------------------------------------------
__global__ void kuramoto_kernel(const float* __restrict__ omega,
                                const float* __restrict__ theta0,
                                const float* __restrict__ cK,
                                float* __restrict__ out_tail,
                                float* __restrict__ phase_mod) {
    __shared__ float ph[H_];
    __shared__ float mc_s, ms_s;
    const int i = threadIdx.x;
    if (i < H_) {
        const float ti = theta0[i];
        float s = 0.f;
        for (int j = 0; j < H_; ++j) s += cK[i * H_ + j] * sinf(theta0[j] - ti);
        ph[i] = ti + 0.1f * (omega[i] + (1.0f / H_) * s);
    }
    __syncthreads();
    if (i == 0) {
        float mc = 0.f, ms = 0.f;
        for (int j = 0; j < H_; ++j) { mc += cosf(ph[j]); ms += sinf(ph[j]); }
        mc *= (1.0f / H_); ms *= (1.0f / H_);
        mc_s = mc; ms_s = ms;
        const float ord = sqrtf(mc * mc + ms * ms);
        out_tail[B_ * H_ + 0] = ord;
        out_tail[B_ * H_ + 1] = ord;
    }
    __syncthreads();
    if (i < H_) {
        const float p = ph[i];
        const float pmv = cosf(p) * mc_s + sinf(p) * ms_s;
        out_tail[i] = p;
        out_tail[H_ + i] = p;
        phase_mod[i] = pmv;
        phase_mod[H_ + i] = pmv;
    }
}

// ---------------------------------------------------------------------------
// bf16 MFMA GEMM: C = A @ W^T + bias.  A:[M,K] bf16, W:[N,K] bf16.
// 128x128 tile, BK=32, 256 thr = 4 waves (2x2), 64x64 per wave, 4x4 frags.
// MODE 0: N=3072 fused QKV -> Q/K head-layout bf16, V transposed bf16.
// MODE 1: fp32 [M,N] output (+bias b0).
// ---------------------------------------------------------------------------
template<int MODE>
__global__ __launch_bounds__(256)
void mfma_gemm(const unsigned short* __restrict__ A, const unsigned short* __restrict__ W,
               const float* __restrict__ b0, const float* __restrict__ b1,
               const float* __restrict__ b2,
               unsigned short* __restrict__ Qo, unsigned short* __restrict__ Ko,
               unsigned short* __restrict__ Vto, float* __restrict__ Fo,
               int M, int N, int Kd) {
    __shared__ unsigned short As[128 * 32];
    __shared__ unsigned short Bs[128 * 32];
    const int t = threadIdx.x;
    const int wave = t >> 6, lane = t & 63;
    const int wr = wave >> 1, wc = wave & 1;
    const int m0 = blockIdx.y * 128;
    const int n0g = blockIdx.x * 128;

    const f32x4 vzero = {0.f, 0.f, 0.f, 0.f};
    f32x4 acc[4][4];
#pragma unroll
    for (int i = 0; i < 4; ++i)
#pragma unroll
        for (int j = 0; j < 4; ++j) acc[i][j] = vzero;

    const int srow = lane >> 2;     // row within 16-row chunk (64B rows)
    const int sun  = lane & 3;      // 16B unit within row

    for (int k0 = 0; k0 < Kd; k0 += 32) {
        __syncthreads();
#pragma unroll
        for (int c = 0; c < 2; ++c) {
            const int ch  = wave * 2 + c;
            const int row = ch * 16 + srow;              // 0..127
            const int gu  = sun ^ ((row >> 1) & 3);      // pre-swizzled source
            gld_lds16(A + (size_t)(m0 + row) * Kd + k0 + gu * 8, &As[ch * 512]);
            gld_lds16(W + (size_t)(n0g + row) * Kd + k0 + gu * 8, &Bs[ch * 512]);
        }
        __syncthreads();

        short8 af[4], bf[4];
#pragma unroll
        for (int mf = 0; mf < 4; ++mf) {
            const int row = wr * 64 + mf * 16 + (lane & 15);
            const int pu  = (lane >> 4) ^ ((row >> 1) & 3);
            af[mf] = *(const short8*)&As[row * 32 + pu * 8];
        }
#pragma unroll
        for (int nf = 0; nf < 4; ++nf) {
            const int row = wc * 64 + nf * 16 + (lane & 15);
            const int pu  = (lane >> 4) ^ ((row >> 1) & 3);
            bf[nf] = *(const short8*)&Bs[row * 32 + pu * 8];
        }
#pragma unroll
        for (int mf = 0; mf < 4; ++mf)
#pragma unroll
            for (int nf = 0; nf < 4; ++nf)
                acc[mf][nf] = __builtin_amdgcn_mfma_f32_16x16x32_bf16(
                    af[mf], bf[nf], acc[mf][nf], 0, 0, 0);
    }

    const int matsel = n0g >> 10;
    const int nb = n0g & 1023;
#pragma unroll
    for (int mf = 0; mf < 4; ++mf) {
#pragma unroll
        for (int nf = 0; nf < 4; ++nf) {
            const int n_loc  = wc * 64 + nf * 16 + (lane & 15);
            const int m_base = m0 + wr * 64 + mf * 16 + ((lane >> 4) << 2);
            const int n = nb + n_loc;                    // col within its matrix
            if (MODE == 1) {
                const float bias = b0[n];
#pragma unroll
                for (int r = 0; r < 4; ++r)
                    Fo[(size_t)(m_base + r) * N + n] = acc[mf][nf][r] + bias;
            } else {
                const float bias = (matsel == 0 ? b0 : matsel == 1 ? b1 : b2)[n];
                const int h = n >> 6, d = n & 63;
                const int b = m_base >> 10, lb = m_base & 1023;
                const int bh = b * 16 + h;
                if (matsel < 2) {
                    unsigned short* dst = (matsel == 0 ? Qo : Ko);
#pragma unroll
                    for (int r = 0; r < 4; ++r)
                        dst[((size_t)bh * L_ + lb + r) * HD_ + d] =
                            f2b(acc[mf][nf][r] + bias);
                } else {
                    ushort4 o;
                    o.x = f2b(acc[mf][nf][0] + bias);
                    o.y = f2b(acc[mf][nf][1] + bias);
                    o.z = f2b(acc[mf][nf][2] + bias);
                    o.w = f2b(acc[mf][nf][3] + bias);
                    *(ushort4*)&Vto[((size_t)bh * HD_ + d) * L_ + lb] = o;
                }
            }
        }
    }
}

// ---------------------------------------------------------------------------
// MFMA flash attention.  Grid (L/64, B*H), 256 thr = 4 waves.
// Wave w owns q-rows [l0+16w, +16).  Q frags + qn in registers.
// K tile [64s][64d] and Vt tile [64d][64s] staged swizzled via global_load_lds.
// No running max: scores = pm/z are bounded in [-1,1] -> p = exp(score).
// ---------------------------------------------------------------------------
__global__ __launch_bounds__(256)
void attn_mfma_kernel(const unsigned short* __restrict__ Qg,
                      const unsigned short* __restrict__ Kg,
                      const unsigned short* __restrict__ Vtg,
                      const u64* __restrict__ mb,
                      const float* __restrict__ pm_arr,
                      unsigned short* __restrict__ ctx) {
    __shared__ unsigned short Ks[64 * 64];
    __shared__ unsigned short Vs[64 * 64];
    __shared__ unsigned short Ps[4][16 * 64];
    const int bh = blockIdx.y, b = bh >> 4, h = bh & 15;
    const int l0 = blockIdx.x << 6;
    const int t = threadIdx.x, wave = t >> 6, lane = t & 63;
    const float pm = pm_arr[bh];
    const f32x4 vzero = {0.f, 0.f, 0.f, 0.f};

    // Q fragments (A-operand) + qn, all in registers
    short8 aq[2];
    {
        const int qrow = l0 + wave * 16 + (lane & 15);
        const size_t qb = ((size_t)bh * L_ + qrow) * HD_ + ((lane >> 4) << 3);
        aq[0] = *(const short8*)&Qg[qb];
        aq[1] = *(const short8*)&Qg[qb + 32];
    }
    float qnv = 0.f;
#pragma unroll
    for (int ks = 0; ks < 2; ++ks)
#pragma unroll
        for (int e = 0; e < 8; ++e) { const float v = b2f(aq[ks][e]); qnv = fmaf(v, v, qnv); }
    qnv += __shfl_xor(qnv, 16);
    qnv += __shfl_xor(qnv, 32);
    float qn_row[4], omq[4];
#pragma unroll
    for (int r = 0; r < 4; ++r) {
        qn_row[r] = __shfl(qnv, ((lane >> 4) << 2) + r);
        omq[r] = 1.f - fminf(qn_row[r], 0.99f);
    }

    f32x4 oacc[4];
#pragma unroll
    for (int nf = 0; nf < 4; ++nf) oacc[nf] = vzero;
    float rowsum[4] = {0.f, 0.f, 0.f, 0.f};

    const int srow = lane >> 3;   // staging: row within 8-row chunk (128B rows)
    const int sun  = lane & 7;    // 16B unit within row

    for (int s0 = 0; s0 < L_; s0 += 64) {
        __syncthreads();
#pragma unroll
        for (int c = 0; c < 2; ++c) {
            const int ch  = wave * 2 + c;
            const int row = ch * 8 + srow;          // 0..63
            const int gu  = sun ^ (row & 7);        // pre-swizzled source
            gld_lds16(Kg  + ((size_t)bh * L_  + s0 + row) * HD_ + gu * 8, &Ks[ch * 512]);
            gld_lds16(Vtg + ((size_t)bh * HD_ + row) * L_  + s0 + gu * 8, &Vs[ch * 512]);
        }
        __syncthreads();

        // K fragments (B-operand), kn, QK^T
        short8 bk_[4][2];
        f32x4 c[4];
        float kn_[4];
#pragma unroll
        for (int f = 0; f < 4; ++f) {
            const int row = (f << 4) + (lane & 15);  // s within tile
#pragma unroll
            for (int ks = 0; ks < 2; ++ks) {
                const int pu = ((ks << 2) + (lane >> 4)) ^ (row & 7);
                bk_[f][ks] = *(const short8*)&Ks[(row << 6) + (pu << 3)];
            }
            float kn = 0.f;
#pragma unroll
            for (int ks = 0; ks < 2; ++ks)
#pragma unroll
                for (int e = 0; e < 8; ++e) { const float v = b2f(bk_[f][ks][e]); kn = fmaf(v, v, kn); }
            kn += __shfl_xor(kn, 16);
            kn += __shfl_xor(kn, 32);
            kn_[f] = kn;
            c[f] = vzero;
            c[f] = __builtin_amdgcn_mfma_f32_16x16x32_bf16(aq[0], bk_[f][0], c[f], 0, 0, 0);
            c[f] = __builtin_amdgcn_mfma_f32_16x16x32_bf16(aq[1], bk_[f][1], c[f], 0, 0, 0);
        }

        // mask bits for this wave's 16 rows x this 64-col tile
        u64 mrow[4];
#pragma unroll
        for (int r = 0; r < 4; ++r) {
            const int lrow = l0 + wave * 16 + ((lane >> 4) << 2) + r;
            mrow[r] = mb[((size_t)b * L_ + lrow) * (L_ / 64) + (s0 >> 6)];
        }

        // score transform + P write (per-wave LDS, swizzled)
        unsigned short* Pw = &Ps[wave][0];
#pragma unroll
        for (int f = 0; f < 4; ++f) {
            const float kv  = kn_[f];
            const float omk = 1.f - fminf(kv, 0.99f);
            const int col = (f << 4) + (lane & 15);
#pragma unroll
            for (int r = 0; r < 4; ++r) {
                const float dot  = c[f][r];
                const float diff = fmaxf(qn_row[r] + kv - 2.f * dot, 0.f);
                const float den  = omq[r] * omk + 1e-8f;
                const float arg  = 1.f + __fdividef(2.f * diff, den);
                const float z    = arg + sqrtf(fmaxf(arg * arg - 1.f, 1e-8f));
                const float sc   = __fdividef(pm, z);
                const float p    = ((mrow[r] >> col) & 1) ? __expf(sc) : 0.f;
                rowsum[r] += p;
                const int prow = ((lane >> 4) << 2) + r;
                const int pu2  = (col >> 3) ^ (prow & 7);
                Pw[(prow << 6) + (pu2 << 3) + (col & 7)] = f2b(p);
            }
        }

        // V fragments (B-operand)
        short8 bv_[4][2];
#pragma unroll
        for (int nf = 0; nf < 4; ++nf) {
            const int row = (nf << 4) + (lane & 15);  // d
#pragma unroll
            for (int ks = 0; ks < 2; ++ks) {
                const int pu = ((ks << 2) + (lane >> 4)) ^ (row & 7);
                bv_[nf][ks] = *(const short8*)&Vs[(row << 6) + (pu << 3)];
            }
        }
        // P fragments (A-operand) + PV
#pragma unroll
        for (int ks = 0; ks < 2; ++ks) {
            const int m  = lane & 15;
            const int pu = ((ks << 2) + (lane >> 4)) ^ (m & 7);
            const short8 ap = *(const short8*)&Pw[(m << 6) + (pu << 3)];
#pragma unroll
            for (int nf = 0; nf < 4; ++nf)
                oacc[nf] = __builtin_amdgcn_mfma_f32_16x16x32_bf16(ap, bv_[nf][ks], oacc[nf], 0, 0, 0);
        }
    }

    // normalize + write ctx (bf16 [B,L,D])
#pragma unroll
    for (int r = 0; r < 4; ++r) {
        rowsum[r] += __shfl_xor(rowsum[r], 1);
        rowsum[r] += __shfl_xor(rowsum[r], 2);
        rowsum[r] += __shfl_xor(rowsum[r], 4);
        rowsum[r] += __shfl_xor(rowsum[r], 8);
        rowsum[r] = __fdividef(1.f, rowsum[r]);
    }
#pragma unroll
    for (int nf = 0; nf < 4; ++nf) {
        const int d = (nf << 4) + (lane & 15);
#pragma unroll
        for (int r = 0; r < 4; ++r) {
            const int lrow = l0 + wave * 16 + ((lane >> 4) << 2) + r;
            ctx[((size_t)b * L_ + lrow) * D_ + (h << 6) + d] = f2b(oacc[nf][r] * rowsum[r]);
        }
    }
}

// ---------------------------------------------------------------------------
extern "C" void kernel_launch(void* const* d_in, const int* in_sizes, int n_in,
                              void* d_out, int out_size, void* d_ws, size_t ws_size,
                              hipStream_t stream) {
    const float* hs     = (const float*)d_in[0];
    const int*   mask   = (const int*)  d_in[1];
    const float* Wq     = (const float*)d_in[2];
    const float* bq     = (const float*)d_in[3];
    const float* Wk     = (const float*)d_in[4];
    const float* bk     = (const float*)d_in[5];
    const float* Wv     = (const float*)d_in[6];
    const float* bv     = (const float*)d_in[7];
    const float* Wo     = (const float*)d_in[8];
    const float* bo     = (const float*)d_in[9];
    const float* omega  = (const float*)d_in[10];
    const float* theta0 = (const float*)d_in[11];
    const float* cK     = (const float*)d_in[12];
    float* out = (float*)d_out;

    char* ws = (char*)d_ws;
    unsigned short* hsb  = (unsigned short*)ws;                 ws += (size_t)2097152 * 2;
    unsigned short* Wcb  = (unsigned short*)ws;                 ws += (size_t)3145728 * 2;
    unsigned short* Wob  = (unsigned short*)ws;                 ws += (size_t)1048576 * 2;
    unsigned short* Qb   = (unsigned short*)ws;                 ws += (size_t)2097152 * 2;
    unsigned short* Kb   = (unsigned short*)ws;                 ws += (size_t)2097152 * 2;
    unsigned short* Vtb  = (unsigned short*)ws;                 ws += (size_t)2097152 * 2;
    unsigned short* ctxb = (unsigned short*)ws;                 ws += (size_t)2097152 * 2;
    u64*            mbits= (u64*)ws;                            ws += (size_t)32768 * 8;
    float*          pmf  = (float*)ws;

    cast4_kernel<<<2048, 256, 0, stream>>>(hs, hsb, 524288);
    cast4_kernel<<<1024, 256, 0, stream>>>(Wq, Wcb,           262144);
    cast4_kernel<<<1024, 256, 0, stream>>>(Wk, Wcb + 1048576, 262144);
    cast4_kernel<<<1024, 256, 0, stream>>>(Wv, Wcb + 2097152, 262144);
    cast4_kernel<<<1024, 256, 0, stream>>>(Wo, Wob,           262144);
    pack_mask_kernel<<<8192, 256, 0, stream>>>(mask, mbits, 2097152);
    kuramoto_kernel<<<1, 64, 0, stream>>>(omega, theta0, cK,
                                          out + (size_t)B_ * L_ * D_, pmf);

    mfma_gemm<0><<<dim3(24, 16), 256, 0, stream>>>(hsb, Wcb, bq, bk, bv,
                                                   Qb, Kb, Vtb, nullptr,
                                                   2048, 3072, 1024);
    attn_mfma_kernel<<<dim3(16, 32), 256, 0, stream>>>(Qb, Kb, Vtb, mbits, pmf, ctxb);
    mfma_gemm<1><<<dim3(8, 16), 256, 0, stream>>>(ctxb, Wob, bo, nullptr, nullptr,
                                                  nullptr, nullptr, nullptr, out,
                                                  2048, 1024, 1024);
}

// Round 3
// 199.050 us; speedup vs baseline: 3.0123x; 1.2233x over previous
//
#include <hip/hip_runtime.h>
#include <hip/hip_bf16.h>
#include <math.h>

#define B_  2
#define L_  1024
#define D_  1024
#define H_  16
#define HD_ 64

typedef __attribute__((ext_vector_type(8))) short short8;
typedef __attribute__((ext_vector_type(4))) float f32x4;
typedef unsigned int u32;
typedef unsigned long long u64;
typedef unsigned short ushort_t;

__device__ inline float b2f(short s) {
    union { float f; u32 i; } c; c.i = ((u32)(unsigned short)s) << 16; return c.f;
}
__device__ inline unsigned short f2b(float f) {
    __hip_bfloat16 h = __float2bfloat16(f);
    return *reinterpret_cast<unsigned short*>(&h);
}
__device__ inline void gld_lds16(const void* g, void* l) {
    __builtin_amdgcn_global_load_lds((const __attribute__((address_space(1))) u32*)g,
                                     (__attribute__((address_space(3))) u32*)l, 16, 0, 0);
}

// ---------------------------------------------------------------------------
// all fp32->bf16 casts in one launch
// ---------------------------------------------------------------------------
__global__ void cast_all_kernel(const float* __restrict__ hs, const float* __restrict__ Wq,
                                const float* __restrict__ Wk, const float* __restrict__ Wv,
                                const float* __restrict__ Wo,
                                ushort_t* __restrict__ hsb, ushort_t* __restrict__ Wcb,
                                ushort_t* __restrict__ Wob) {
    const int blk = blockIdx.x;
    const float* src; ushort_t* dst; int idx;
    if (blk < 2048)      { src = hs; dst = hsb;           idx = blk * 256 + threadIdx.x; }
    else if (blk < 3072) { src = Wq; dst = Wcb;           idx = (blk - 2048) * 256 + threadIdx.x; }
    else if (blk < 4096) { src = Wk; dst = Wcb + 1048576; idx = (blk - 3072) * 256 + threadIdx.x; }
    else if (blk < 5120) { src = Wv; dst = Wcb + 2097152; idx = (blk - 4096) * 256 + threadIdx.x; }
    else                 { src = Wo; dst = Wob;           idx = (blk - 5120) * 256 + threadIdx.x; }
    float4 v = ((const float4*)src)[idx];
    ushort4 o;
    o.x = f2b(v.x); o.y = f2b(v.y); o.z = f2b(v.z); o.w = f2b(v.w);
    ((ushort4*)dst)[idx] = o;
}

// ---------------------------------------------------------------------------
// mask [B,1,L,L] int -> bitmask u64 per 64 s-cols
// ---------------------------------------------------------------------------
__global__ void pack_mask_kernel(const int* __restrict__ mask,
                                 u64* __restrict__ bits, int n) {
    const int i = blockIdx.x * 256 + threadIdx.x;
    const int v = (i < n) ? mask[i] : 1;
    const u64 bal = __ballot(v != 0);
    if ((threadIdx.x & 63) == 0 && i < n) bits[i >> 6] = bal;
}

// ---------------------------------------------------------------------------
// row norms from bf16 Q/K: qnrq = {qn, 2/(1-min(qn,.99))}, knrk = {kn, 1/(1-min(kn,.99))}
// 8 lanes per row, 8 rows per wave.
// ---------------------------------------------------------------------------
__global__ __launch_bounds__(256)
void rownorms_kernel(const ushort_t* __restrict__ Qb, const ushort_t* __restrict__ Kb,
                     float2* __restrict__ qnrq, float2* __restrict__ knrk) {
    const int t = threadIdx.x, lane = t & 63;
    const int wid = (blockIdx.x * 256 + t) >> 6;        // 0..8191
    const int rid = wid * 8 + (lane >> 3);              // 0..65535
    const bool isQ = rid < 32768;
    const int r = isQ ? rid : rid - 32768;
    const ushort_t* src = isQ ? Qb : Kb;
    short8 v = *(const short8*)&src[(size_t)r * HD_ + ((lane & 7) << 3)];
    float s = 0.f;
#pragma unroll
    for (int e = 0; e < 8; ++e) { const float x = b2f(v[e]); s = fmaf(x, x, s); }
    s += __shfl_xor(s, 1);
    s += __shfl_xor(s, 2);
    s += __shfl_xor(s, 4);
    if ((lane & 7) == 0) {
        const float om = 1.f - fminf(s, 0.99f);
        if (isQ) qnrq[r] = make_float2(s, __fdividef(2.f, om));
        else     knrk[r] = make_float2(s, __fdividef(1.f, om));
    }
}

// ---------------------------------------------------------------------------
// Kuramoto step (tiny)
// ---------------------------------------------------------------------------
__global__ void kuramoto_kernel(const float* __restrict__ omega,
                                const float* __restrict__ theta0,
                                const float* __restrict__ cK,
                                float* __restrict__ out_tail,
                                float* __restrict__ phase_mod) {
    __shared__ float ph[H_];
    __shared__ float mc_s, ms_s;
    const int i = threadIdx.x;
    if (i < H_) {
        const float ti = theta0[i];
        float s = 0.f;
        for (int j = 0; j < H_; ++j) s += cK[i * H_ + j] * sinf(theta0[j] - ti);
        ph[i] = ti + 0.1f * (omega[i] + (1.0f / H_) * s);
    }
    __syncthreads();
    if (i == 0) {
        float mc = 0.f, ms = 0.f;
        for (int j = 0; j < H_; ++j) { mc += cosf(ph[j]); ms += sinf(ph[j]); }
        mc *= (1.0f / H_); ms *= (1.0f / H_);
        mc_s = mc; ms_s = ms;
        const float ord = sqrtf(mc * mc + ms * ms);
        out_tail[B_ * H_ + 0] = ord;
        out_tail[B_ * H_ + 1] = ord;
    }
    __syncthreads();
    if (i < H_) {
        const float p = ph[i];
        const float pmv = cosf(p) * mc_s + sinf(p) * ms_s;
        out_tail[i] = p;
        out_tail[H_ + i] = p;
        phase_mod[i] = pmv;
        phase_mod[H_ + i] = pmv;
    }
}

// ---------------------------------------------------------------------------
// bf16 MFMA GEMM, C = A @ W^T + bias.  Tile BM x 64, BK=32, 4 waves along M,
// double-buffered LDS, 1 barrier per K-step.
// MODE 0: fused QKV epilogue (Q/K head layout, V transposed).  MODE 1: fp32 out.
// ---------------------------------------------------------------------------
template<int BM, int MODE>
__global__ __launch_bounds__(256)
void mfma_gemm(const ushort_t* __restrict__ A, const ushort_t* __restrict__ W,
               const float* __restrict__ b0, const float* __restrict__ b1,
               const float* __restrict__ b2,
               ushort_t* __restrict__ Qo, ushort_t* __restrict__ Ko,
               ushort_t* __restrict__ Vto, float* __restrict__ Fo,
               int N, int Kd) {
    constexpr int MF = BM / 64;                 // m-frags per wave (2 or 1)
    __shared__ ushort_t As[2][BM * 32];
    __shared__ ushort_t Bs[2][64 * 32];
    const int t = threadIdx.x, wave = t >> 6, lane = t & 63;
    const int m0 = blockIdx.y * BM, n0g = blockIdx.x * 64;

    const f32x4 vzero = {0.f, 0.f, 0.f, 0.f};
    f32x4 acc[MF][4];
#pragma unroll
    for (int i = 0; i < MF; ++i)
#pragma unroll
        for (int j = 0; j < 4; ++j) acc[i][j] = vzero;

    const int srow = lane >> 2, sun = lane & 3;   // 64B rows, 16B units

    auto stage = [&](int bufi, int k0) {
#pragma unroll
        for (int c = 0; c < MF; ++c) {
            const int ch  = wave * MF + c;
            const int row = ch * 16 + srow;
            const int gu  = sun ^ ((row >> 1) & 3);
            gld_lds16(A + (size_t)(m0 + row) * Kd + k0 + gu * 8, &As[bufi][ch * 512]);
        }
        const int row = wave * 16 + srow;
        const int gu  = sun ^ ((row >> 1) & 3);
        gld_lds16(W + (size_t)(n0g + row) * Kd + k0 + gu * 8, &Bs[bufi][wave * 512]);
    };

    stage(0, 0);
    __syncthreads();
    const int NK = Kd >> 5;
    int buf = 0;
    for (int it = 0; it < NK; ++it) {
        if (it + 1 < NK) stage(buf ^ 1, (it + 1) << 5);
        short8 af[MF], bf[4];
#pragma unroll
        for (int mf = 0; mf < MF; ++mf) {
            const int row = wave * (16 * MF) + mf * 16 + (lane & 15);
            const int pu  = (lane >> 4) ^ ((row >> 1) & 3);
            af[mf] = *(const short8*)&As[buf][row * 32 + pu * 8];
        }
#pragma unroll
        for (int nf = 0; nf < 4; ++nf) {
            const int row = nf * 16 + (lane & 15);
            const int pu  = (lane >> 4) ^ ((row >> 1) & 3);
            bf[nf] = *(const short8*)&Bs[buf][row * 32 + pu * 8];
        }
#pragma unroll
        for (int mf = 0; mf < MF; ++mf)
#pragma unroll
            for (int nf = 0; nf < 4; ++nf)
                acc[mf][nf] = __builtin_amdgcn_mfma_f32_16x16x32_bf16(
                    af[mf], bf[nf], acc[mf][nf], 0, 0, 0);
        __syncthreads();
        buf ^= 1;
    }

    const int matsel = n0g >> 10;
    const int nb = n0g & 1023;
#pragma unroll
    for (int mf = 0; mf < MF; ++mf) {
        const int m_base = m0 + wave * (16 * MF) + mf * 16 + ((lane >> 4) << 2);
#pragma unroll
        for (int nf = 0; nf < 4; ++nf) {
            const int n = nb + nf * 16 + (lane & 15);
            if (MODE == 1) {
                const float bias = b0[n];
#pragma unroll
                for (int r = 0; r < 4; ++r)
                    Fo[(size_t)(m_base + r) * N + n] = acc[mf][nf][r] + bias;
            } else {
                const float bias = (matsel == 0 ? b0 : matsel == 1 ? b1 : b2)[n];
                const int h = n >> 6, d = n & 63;
                const int b = m_base >> 10, lb = m_base & 1023;
                const int bh = b * 16 + h;
                if (matsel < 2) {
                    ushort_t* dst = (matsel == 0 ? Qo : Ko);
#pragma unroll
                    for (int r = 0; r < 4; ++r)
                        dst[((size_t)bh * L_ + lb + r) * HD_ + d] =
                            f2b(acc[mf][nf][r] + bias);
                } else {
                    ushort4 o;
                    o.x = f2b(acc[mf][nf][0] + bias);
                    o.y = f2b(acc[mf][nf][1] + bias);
                    o.z = f2b(acc[mf][nf][2] + bias);
                    o.w = f2b(acc[mf][nf][3] + bias);
                    *(ushort4*)&Vto[((size_t)bh * HD_ + d) * L_ + lb] = o;
                }
            }
        }
    }
}

// ---------------------------------------------------------------------------
// MFMA flash attention, double-buffered K/V, precomputed norms, cheap transform.
// score = pm*(arg - sqrt(arg^2-1)) == pm*exp(-dist);  p = exp2(pm*log2e*(...)).
// ---------------------------------------------------------------------------
__global__ __launch_bounds__(256)
void attn_mfma_kernel(const ushort_t* __restrict__ Qg,
                      const ushort_t* __restrict__ Kg,
                      const ushort_t* __restrict__ Vtg,
                      const u64* __restrict__ mb,
                      const float* __restrict__ pm_arr,
                      const float2* __restrict__ qnrq,
                      const float2* __restrict__ knrk,
                      ushort_t* __restrict__ ctx) {
    __shared__ ushort_t Ks[2][64 * 64];
    __shared__ ushort_t Vs[2][64 * 64];
    __shared__ ushort_t Ps[4][16 * 64];
    const int bh = blockIdx.y, b = bh >> 4, h = bh & 15;
    const int l0 = blockIdx.x << 6;
    const int t = threadIdx.x, wave = t >> 6, lane = t & 63;
    const float pm2 = pm_arr[bh] * 1.44269504f;
    const f32x4 vzero = {0.f, 0.f, 0.f, 0.f};

    // Q fragments (A-operand) in registers
    short8 aq[2];
    {
        const int qrow = l0 + wave * 16 + (lane & 15);
        const size_t qb = ((size_t)bh * L_ + qrow) * HD_ + ((lane >> 4) << 3);
        aq[0] = *(const short8*)&Qg[qb];
        aq[1] = *(const short8*)&Qg[qb + 32];
    }
    // per-row qn, rq (precomputed)
    float qn_row[4], rq_row[4];
#pragma unroll
    for (int r = 0; r < 4; ++r) {
        const float2 qv = qnrq[bh * L_ + l0 + wave * 16 + ((lane >> 4) << 2) + r];
        qn_row[r] = qv.x; rq_row[r] = qv.y;
    }

    f32x4 oacc[4];
#pragma unroll
    for (int nf = 0; nf < 4; ++nf) oacc[nf] = vzero;
    float rowsum[4] = {0.f, 0.f, 0.f, 0.f};

    const int srow = lane >> 3, sun = lane & 7;   // 128B rows, 16B units

    auto stage = [&](int bufi, int s0) {
#pragma unroll
        for (int c = 0; c < 2; ++c) {
            const int ch  = wave * 2 + c;
            const int row = ch * 8 + srow;
            const int gu  = sun ^ (row & 7);
            gld_lds16(Kg  + ((size_t)bh * L_  + s0 + row) * HD_ + gu * 8, &Ks[bufi][ch * 512]);
            gld_lds16(Vtg + ((size_t)bh * HD_ + row) * L_  + s0 + gu * 8, &Vs[bufi][ch * 512]);
        }
    };

    stage(0, 0);
    __syncthreads();
    int buf = 0;
    for (int s0 = 0; s0 < L_; s0 += 64) {
        if (s0 + 64 < L_) stage(buf ^ 1, s0 + 64);

        // mask bits (pre-split u64 -> 2x u32)
        u32 mlo[4], mhi[4];
#pragma unroll
        for (int r = 0; r < 4; ++r) {
            const int lrow = l0 + wave * 16 + ((lane >> 4) << 2) + r;
            const u64 m = mb[((size_t)b * L_ + lrow) * (L_ / 64) + (s0 >> 6)];
            mlo[r] = (u32)m; mhi[r] = (u32)(m >> 32);
        }
        // per-col kn, rk (precomputed)
        float2 kk[4];
#pragma unroll
        for (int f = 0; f < 4; ++f)
            kk[f] = knrk[bh * L_ + s0 + (f << 4) + (lane & 15)];

        // K fragments + QK^T
        short8 bk_[4][2];
#pragma unroll
        for (int f = 0; f < 4; ++f) {
            const int row = (f << 4) + (lane & 15);
#pragma unroll
            for (int ks = 0; ks < 2; ++ks) {
                const int pu = ((ks << 2) + (lane >> 4)) ^ (row & 7);
                bk_[f][ks] = *(const short8*)&Ks[buf][(row << 6) + (pu << 3)];
            }
        }
        f32x4 c[4];
#pragma unroll
        for (int f = 0; f < 4; ++f) {
            c[f] = vzero;
            c[f] = __builtin_amdgcn_mfma_f32_16x16x32_bf16(aq[0], bk_[f][0], c[f], 0, 0, 0);
            c[f] = __builtin_amdgcn_mfma_f32_16x16x32_bf16(aq[1], bk_[f][1], c[f], 0, 0, 0);
        }
        // V fragments (independent of transform -> overlaps MFMA latency)
        short8 bv_[4][2];
#pragma unroll
        for (int nf = 0; nf < 4; ++nf) {
            const int row = (nf << 4) + (lane & 15);
#pragma unroll
            for (int ks = 0; ks < 2; ++ks) {
                const int pu = ((ks << 2) + (lane >> 4)) ^ (row & 7);
                bv_[nf][ks] = *(const short8*)&Vs[buf][(row << 6) + (pu << 3)];
            }
        }

        // score transform + P write
        ushort_t* Pw = &Ps[wave][0];
#pragma unroll
        for (int f = 0; f < 4; ++f) {
            const int colc = (f << 4) + (lane & 15);
            const int sh   = ((f & 1) << 4) + (lane & 15);
            const float knv = kk[f].x, rkv = kk[f].y;
#pragma unroll
            for (int r = 0; r < 4; ++r) {
                const float diff = fmaxf(fmaf(-2.f, c[f][r], qn_row[r] + knv), 0.f);
                const float arg  = fmaf(diff * rq_row[r], rkv, 1.f);
                const float srt  = sqrtf(fmaf(arg, arg, -1.f));   // exact fma => >= 0
                float p = exp2f(pm2 * (arg - srt));
                const u32 bits = (f < 2) ? mlo[r] : mhi[r];
                p = ((bits >> sh) & 1) ? p : 0.f;
                rowsum[r] += p;
                const int prow = ((lane >> 4) << 2) + r;
                const int pu2  = (colc >> 3) ^ (prow & 7);
                Pw[(prow << 6) + (pu2 << 3) + (colc & 7)] = f2b(p);
            }
        }

        // P fragments + PV
#pragma unroll
        for (int ks = 0; ks < 2; ++ks) {
            const int m  = lane & 15;
            const int pu = ((ks << 2) + (lane >> 4)) ^ (m & 7);
            const short8 ap = *(const short8*)&Pw[(m << 6) + (pu << 3)];
#pragma unroll
            for (int nf = 0; nf < 4; ++nf)
                oacc[nf] = __builtin_amdgcn_mfma_f32_16x16x32_bf16(ap, bv_[nf][ks], oacc[nf], 0, 0, 0);
        }
        __syncthreads();
        buf ^= 1;
    }

    // normalize + write ctx (bf16 [B,L,D])
#pragma unroll
    for (int r = 0; r < 4; ++r) {
        rowsum[r] += __shfl_xor(rowsum[r], 1);
        rowsum[r] += __shfl_xor(rowsum[r], 2);
        rowsum[r] += __shfl_xor(rowsum[r], 4);
        rowsum[r] += __shfl_xor(rowsum[r], 8);
        rowsum[r] = __fdividef(1.f, rowsum[r]);
    }
#pragma unroll
    for (int nf = 0; nf < 4; ++nf) {
        const int d = (nf << 4) + (lane & 15);
#pragma unroll
        for (int r = 0; r < 4; ++r) {
            const int lrow = l0 + wave * 16 + ((lane >> 4) << 2) + r;
            ctx[((size_t)b * L_ + lrow) * D_ + (h << 6) + d] = f2b(oacc[nf][r] * rowsum[r]);
        }
    }
}

// ---------------------------------------------------------------------------
extern "C" void kernel_launch(void* const* d_in, const int* in_sizes, int n_in,
                              void* d_out, int out_size, void* d_ws, size_t ws_size,
                              hipStream_t stream) {
    const float* hs     = (const float*)d_in[0];
    const int*   mask   = (const int*)  d_in[1];
    const float* Wq     = (const float*)d_in[2];
    const float* bq     = (const float*)d_in[3];
    const float* Wk     = (const float*)d_in[4];
    const float* bk     = (const float*)d_in[5];
    const float* Wv     = (const float*)d_in[6];
    const float* bv     = (const float*)d_in[7];
    const float* Wo     = (const float*)d_in[8];
    const float* bo     = (const float*)d_in[9];
    const float* omega  = (const float*)d_in[10];
    const float* theta0 = (const float*)d_in[11];
    const float* cK     = (const float*)d_in[12];
    float* out = (float*)d_out;

    char* ws = (char*)d_ws;
    ushort_t* hsb  = (ushort_t*)ws;  ws += (size_t)2097152 * 2;
    ushort_t* Wcb  = (ushort_t*)ws;  ws += (size_t)3145728 * 2;
    ushort_t* Wob  = (ushort_t*)ws;  ws += (size_t)1048576 * 2;
    ushort_t* Qb   = (ushort_t*)ws;  ws += (size_t)2097152 * 2;
    ushort_t* Kb   = (ushort_t*)ws;  ws += (size_t)2097152 * 2;
    ushort_t* Vtb  = (ushort_t*)ws;  ws += (size_t)2097152 * 2;
    ushort_t* ctxb = (ushort_t*)ws;  ws += (size_t)2097152 * 2;
    u64*      mbits= (u64*)ws;       ws += (size_t)32768 * 8;
    float2*   qnrq = (float2*)ws;    ws += (size_t)32768 * 8;
    float2*   knrk = (float2*)ws;    ws += (size_t)32768 * 8;
    float*    pmf  = (float*)ws;

    cast_all_kernel<<<6144, 256, 0, stream>>>(hs, Wq, Wk, Wv, Wo, hsb, Wcb, Wob);
    pack_mask_kernel<<<8192, 256, 0, stream>>>(mask, mbits, 2097152);
    kuramoto_kernel<<<1, 64, 0, stream>>>(omega, theta0, cK,
                                          out + (size_t)B_ * L_ * D_, pmf);

    mfma_gemm<128, 0><<<dim3(48, 16), 256, 0, stream>>>(hsb, Wcb, bq, bk, bv,
                                                        Qb, Kb, Vtb, nullptr,
                                                        3072, 1024);
    rownorms_kernel<<<2048, 256, 0, stream>>>(Qb, Kb, qnrq, knrk);
    attn_mfma_kernel<<<dim3(16, 32), 256, 0, stream>>>(Qb, Kb, Vtb, mbits, pmf,
                                                       qnrq, knrk, ctxb);
    mfma_gemm<64, 1><<<dim3(16, 32), 256, 0, stream>>>(ctxb, Wob, bo, nullptr, nullptr,
                                                       nullptr, nullptr, nullptr, out,
                                                       1024, 1024);
}

// Round 4
// 189.785 us; speedup vs baseline: 3.1593x; 1.0488x over previous
//
#include <hip/hip_runtime.h>
#include <hip/hip_bf16.h>
#include <math.h>

#define B_  2
#define L_  1024
#define D_  1024
#define H_  16
#define HD_ 64

typedef __attribute__((ext_vector_type(8))) short short8;
typedef __attribute__((ext_vector_type(4))) float f32x4;
typedef unsigned int u32;
typedef unsigned long long u64;
typedef unsigned short ushort_t;

__device__ inline float b2f(short s) {
    union { float f; u32 i; } c; c.i = ((u32)(unsigned short)s) << 16; return c.f;
}
// manual bf16 RNE (no NaN path; inputs always finite here): 3 VALU ops
__device__ inline ushort_t f2b_rne(float f) {
    union { float f; u32 i; } c; c.f = f;
    return (ushort_t)((c.i + 0x7fffu + ((c.i >> 16) & 1u)) >> 16);
}
__device__ inline void gld_lds16(const void* g, void* l) {
    __builtin_amdgcn_global_load_lds((const __attribute__((address_space(1))) u32*)g,
                                     (__attribute__((address_space(3))) u32*)l, 16, 0, 0);
}

// ---------------------------------------------------------------------------
// prep: all fp32->bf16 casts + mask bit-pack + kuramoto in ONE launch
// ---------------------------------------------------------------------------
__global__ __launch_bounds__(256)
void prep_kernel(const float* __restrict__ hs, const float* __restrict__ Wq,
                 const float* __restrict__ Wk, const float* __restrict__ Wv,
                 const float* __restrict__ Wo, const int* __restrict__ mask,
                 const float* __restrict__ omega, const float* __restrict__ theta0,
                 const float* __restrict__ cK,
                 ushort_t* __restrict__ hsb, ushort_t* __restrict__ Wcb,
                 ushort_t* __restrict__ Wob, u64* __restrict__ bits,
                 float* __restrict__ out_tail, float* __restrict__ phase_mod) {
    const int blk = blockIdx.x, t = threadIdx.x;
    if (blk < 6144) {
        const float* src; ushort_t* dst; int idx;
        if (blk < 2048)      { src = hs; dst = hsb;           idx = blk * 256 + t; }
        else if (blk < 3072) { src = Wq; dst = Wcb;           idx = (blk - 2048) * 256 + t; }
        else if (blk < 4096) { src = Wk; dst = Wcb + 1048576; idx = (blk - 3072) * 256 + t; }
        else if (blk < 5120) { src = Wv; dst = Wcb + 2097152; idx = (blk - 4096) * 256 + t; }
        else                 { src = Wo; dst = Wob;           idx = (blk - 5120) * 256 + t; }
        float4 v = ((const float4*)src)[idx];
        ushort4 o;
        o.x = f2b_rne(v.x); o.y = f2b_rne(v.y); o.z = f2b_rne(v.z); o.w = f2b_rne(v.w);
        ((ushort4*)dst)[idx] = o;
    } else if (blk < 14336) {
        const int i = (blk - 6144) * 256 + t;
        const u64 bal = __ballot(mask[i] != 0);
        if ((t & 63) == 0) bits[i >> 6] = bal;
    } else {
        __shared__ float ph[H_];
        __shared__ float mc_s, ms_s;
        if (t < H_) {
            const float ti = theta0[t];
            float s = 0.f;
            for (int j = 0; j < H_; ++j) s += cK[t * H_ + j] * sinf(theta0[j] - ti);
            ph[t] = ti + 0.1f * (omega[t] + (1.0f / H_) * s);
        }
        __syncthreads();
        if (t == 0) {
            float mc = 0.f, ms = 0.f;
            for (int j = 0; j < H_; ++j) { mc += cosf(ph[j]); ms += sinf(ph[j]); }
            mc *= (1.0f / H_); ms *= (1.0f / H_);
            mc_s = mc; ms_s = ms;
            const float ord = sqrtf(mc * mc + ms * ms);
            out_tail[B_ * H_ + 0] = ord;
            out_tail[B_ * H_ + 1] = ord;
        }
        __syncthreads();
        if (t < H_) {
            const float p = ph[t];
            const float pmv = cosf(p) * mc_s + sinf(p) * ms_s;
            out_tail[t] = p;
            out_tail[H_ + t] = p;
            phase_mod[t] = pmv;
            phase_mod[H_ + t] = pmv;
        }
    }
}

// ---------------------------------------------------------------------------
// QKV GEMM: 128x128 tile, BK=32, 4 waves (2x2, 64x64/wave), dbuf LDS.
// Epilogue: Q/K head-layout bf16 + fused row-norms {qn,2/om}/{kn,1/om};
// V transposed bf16 [bh][d][L].
// ---------------------------------------------------------------------------
__global__ __launch_bounds__(256)
void mfma_gemm_qkv(const ushort_t* __restrict__ A, const ushort_t* __restrict__ W,
                   const float* __restrict__ b0, const float* __restrict__ b1,
                   const float* __restrict__ b2,
                   ushort_t* __restrict__ Qo, ushort_t* __restrict__ Ko,
                   ushort_t* __restrict__ Vto,
                   float2* __restrict__ qnrq, float2* __restrict__ knrk) {
    __shared__ ushort_t As[2][4096];
    __shared__ ushort_t Bs[2][4096];
    const int t = threadIdx.x, wave = t >> 6, lane = t & 63;
    const int wr = wave >> 1, wc = wave & 1;
    const int m0 = blockIdx.y * 128, n0g = blockIdx.x * 128;

    const f32x4 vzero = {0.f, 0.f, 0.f, 0.f};
    f32x4 acc[4][4];
#pragma unroll
    for (int i = 0; i < 4; ++i)
#pragma unroll
        for (int j = 0; j < 4; ++j) acc[i][j] = vzero;

    const int srow = lane >> 2, sun = lane & 3;

    auto stage = [&](int bufi, int k0) {
#pragma unroll
        for (int c = 0; c < 2; ++c) {
            const int ch  = wave * 2 + c;
            const int row = ch * 16 + srow;
            const int gu  = sun ^ ((row >> 1) & 3);
            gld_lds16(A + (size_t)(m0 + row) * 1024 + k0 + gu * 8, &As[bufi][ch * 512]);
            gld_lds16(W + (size_t)(n0g + row) * 1024 + k0 + gu * 8, &Bs[bufi][ch * 512]);
        }
    };

    stage(0, 0);
    __syncthreads();
    int buf = 0;
    for (int it = 0; it < 32; ++it) {
        if (it < 31) stage(buf ^ 1, (it + 1) << 5);
        short8 af[4], bf[4];
#pragma unroll
        for (int mf = 0; mf < 4; ++mf) {
            const int row = wr * 64 + mf * 16 + (lane & 15);
            const int pu  = (lane >> 4) ^ ((row >> 1) & 3);
            af[mf] = *(const short8*)&As[buf][row * 32 + pu * 8];
        }
#pragma unroll
        for (int nf = 0; nf < 4; ++nf) {
            const int row = wc * 64 + nf * 16 + (lane & 15);
            const int pu  = (lane >> 4) ^ ((row >> 1) & 3);
            bf[nf] = *(const short8*)&Bs[buf][row * 32 + pu * 8];
        }
#pragma unroll
        for (int mf = 0; mf < 4; ++mf)
#pragma unroll
            for (int nf = 0; nf < 4; ++nf)
                acc[mf][nf] = __builtin_amdgcn_mfma_f32_16x16x32_bf16(
                    af[mf], bf[nf], acc[mf][nf], 0, 0, 0);
        __syncthreads();
        buf ^= 1;
    }

    const int matsel = n0g >> 10, nb = n0g & 1023;
    const int h = (nb + wc * 64) >> 6;
    const float* bias_p = (matsel == 0) ? b0 : (matsel == 1) ? b1 : b2;
    float bias[4];
#pragma unroll
    for (int nf = 0; nf < 4; ++nf)
        bias[nf] = bias_p[nb + wc * 64 + nf * 16 + (lane & 15)];

#pragma unroll
    for (int mf = 0; mf < 4; ++mf) {
        const int mrow = m0 + wr * 64 + mf * 16 + ((lane >> 4) << 2);
        const int bidx = mrow >> 10, lb = mrow & 1023;
        const int bh = bidx * 16 + h;
        if (matsel < 2) {
            ushort_t* dst = (matsel == 0) ? Qo : Ko;
#pragma unroll
            for (int r = 0; r < 4; ++r) {
                float v0 = acc[mf][0][r] + bias[0];
                float v1 = acc[mf][1][r] + bias[1];
                float v2 = acc[mf][2][r] + bias[2];
                float v3 = acc[mf][3][r] + bias[3];
                float s = v0 * v0;
                s = fmaf(v1, v1, s); s = fmaf(v2, v2, s); s = fmaf(v3, v3, s);
                s += __shfl_xor(s, 1); s += __shfl_xor(s, 2);
                s += __shfl_xor(s, 4); s += __shfl_xor(s, 8);
                const size_t rbase = ((size_t)bh * L_ + lb + r) * HD_ + (lane & 15);
                dst[rbase]      = f2b_rne(v0);
                dst[rbase + 16] = f2b_rne(v1);
                dst[rbase + 32] = f2b_rne(v2);
                dst[rbase + 48] = f2b_rne(v3);
                if ((lane & 15) == 0) {
                    const float om = 1.f - fminf(s, 0.99f);
                    if (matsel == 0)
                        qnrq[bh * L_ + lb + r] = make_float2(s, __fdividef(2.f, om));
                    else
                        knrk[bh * L_ + lb + r] = make_float2(s, __fdividef(1.f, om));
                }
            }
        } else {
#pragma unroll
            for (int nf = 0; nf < 4; ++nf) {
                const int d = nf * 16 + (lane & 15);
                ushort4 o;
                o.x = f2b_rne(acc[mf][nf][0] + bias[nf]);
                o.y = f2b_rne(acc[mf][nf][1] + bias[nf]);
                o.z = f2b_rne(acc[mf][nf][2] + bias[nf]);
                o.w = f2b_rne(acc[mf][nf][3] + bias[nf]);
                *(ushort4*)&Vto[((size_t)bh * HD_ + d) * L_ + lb] = o;
            }
        }
    }
}

// ---------------------------------------------------------------------------
// Output projection GEMM: out = ctx @ Wo^T + bo, fp32 out. 64x64 tile, BK=32,
// 4 waves M-stacked, dbuf.
// ---------------------------------------------------------------------------
__global__ __launch_bounds__(256)
void mfma_gemm_out(const ushort_t* __restrict__ A, const ushort_t* __restrict__ W,
                   const float* __restrict__ b0, float* __restrict__ Fo) {
    __shared__ ushort_t As[2][2048];
    __shared__ ushort_t Bs[2][2048];
    const int t = threadIdx.x, wave = t >> 6, lane = t & 63;
    const int m0 = blockIdx.y * 64, n0g = blockIdx.x * 64;

    const f32x4 vzero = {0.f, 0.f, 0.f, 0.f};
    f32x4 acc[4];
#pragma unroll
    for (int j = 0; j < 4; ++j) acc[j] = vzero;

    const int srow = lane >> 2, sun = lane & 3;

    auto stage = [&](int bufi, int k0) {
        const int row = wave * 16 + srow;
        const int gu  = sun ^ ((row >> 1) & 3);
        gld_lds16(A + (size_t)(m0 + row) * 1024 + k0 + gu * 8, &As[bufi][wave * 512]);
        gld_lds16(W + (size_t)(n0g + row) * 1024 + k0 + gu * 8, &Bs[bufi][wave * 512]);
    };

    stage(0, 0);
    __syncthreads();
    int buf = 0;
    for (int it = 0; it < 32; ++it) {
        if (it < 31) stage(buf ^ 1, (it + 1) << 5);
        short8 af, bf[4];
        {
            const int row = wave * 16 + (lane & 15);
            const int pu  = (lane >> 4) ^ ((row >> 1) & 3);
            af = *(const short8*)&As[buf][row * 32 + pu * 8];
        }
#pragma unroll
        for (int nf = 0; nf < 4; ++nf) {
            const int row = nf * 16 + (lane & 15);
            const int pu  = (lane >> 4) ^ ((row >> 1) & 3);
            bf[nf] = *(const short8*)&Bs[buf][row * 32 + pu * 8];
        }
#pragma unroll
        for (int nf = 0; nf < 4; ++nf)
            acc[nf] = __builtin_amdgcn_mfma_f32_16x16x32_bf16(af, bf[nf], acc[nf], 0, 0, 0);
        __syncthreads();
        buf ^= 1;
    }

#pragma unroll
    for (int nf = 0; nf < 4; ++nf) {
        const int n = n0g + nf * 16 + (lane & 15);
        const float bias = b0[n];
        const int m_base = m0 + wave * 16 + ((lane >> 4) << 2);
#pragma unroll
        for (int r = 0; r < 4; ++r)
            Fo[(size_t)(m_base + r) * 1024 + n] = acc[nf][r] + bias;
    }
}

// ---------------------------------------------------------------------------
// MFMA flash attention, slim transform:
//   arg = max(1, 1 + (qn+kn-2dot)*rq*rk);  score = pm/(2*arg)  [rcp approx]
//   p = exp(score) via deg-3 Taylor (|score| <= 0.5)
// ---------------------------------------------------------------------------
__global__ __launch_bounds__(256)
void attn_mfma_kernel(const ushort_t* __restrict__ Qg,
                      const ushort_t* __restrict__ Kg,
                      const ushort_t* __restrict__ Vtg,
                      const u64* __restrict__ mb,
                      const float* __restrict__ pm_arr,
                      const float2* __restrict__ qnrq,
                      const float2* __restrict__ knrk,
                      ushort_t* __restrict__ ctx) {
    __shared__ ushort_t Ks[2][4096];
    __shared__ ushort_t Vs[2][4096];
    __shared__ ushort_t Ps[4][1024];
    const int bh = blockIdx.y, b = bh >> 4, h = bh & 15;
    const int l0 = blockIdx.x << 6;
    const int t = threadIdx.x, wave = t >> 6, lane = t & 63;
    const float pmh = 0.5f * pm_arr[bh];
    const f32x4 vzero = {0.f, 0.f, 0.f, 0.f};

    // Q fragments in registers
    short8 aq[2];
    {
        const int qrow = l0 + wave * 16 + (lane & 15);
        const size_t qb = ((size_t)bh * L_ + qrow) * HD_ + ((lane >> 4) << 3);
        aq[0] = *(const short8*)&Qg[qb];
        aq[1] = *(const short8*)&Qg[qb + 32];
    }
    float qn_row[4], rq_row[4];
#pragma unroll
    for (int r = 0; r < 4; ++r) {
        const float2 qv = qnrq[bh * L_ + l0 + wave * 16 + ((lane >> 4) << 2) + r];
        qn_row[r] = qv.x; rq_row[r] = qv.y;
    }

    // precomputed (s0-invariant) LDS byte/elem offsets
    int ra[8];
#pragma unroll
    for (int f = 0; f < 4; ++f)
#pragma unroll
        for (int ks = 0; ks < 2; ++ks) {
            const int row = (f << 4) + (lane & 15);
            const int pu  = ((ks << 2) + (lane >> 4)) ^ (row & 7);
            ra[f * 2 + ks] = (row << 6) + (pu << 3);
        }
    int pw[16];
#pragma unroll
    for (int f = 0; f < 4; ++f)
#pragma unroll
        for (int r = 0; r < 4; ++r) {
            const int prow = ((lane >> 4) << 2) + r;
            const int colc = (f << 4) + (lane & 15);
            const int pu2  = (colc >> 3) ^ (prow & 7);
            pw[f * 4 + r] = (prow << 6) + (pu2 << 3) + (colc & 7);
        }
    int pr[2];
#pragma unroll
    for (int ks = 0; ks < 2; ++ks) {
        const int m  = lane & 15;
        const int pu = ((ks << 2) + (lane >> 4)) ^ (m & 7);
        pr[ks] = (m << 6) + (pu << 3);
    }

    f32x4 oacc[4];
#pragma unroll
    for (int nf = 0; nf < 4; ++nf) oacc[nf] = vzero;
    float rowsum[4] = {0.f, 0.f, 0.f, 0.f};

    const int srow = lane >> 3, sun = lane & 7;

    auto stage = [&](int bufi, int s0) {
#pragma unroll
        for (int c = 0; c < 2; ++c) {
            const int ch  = wave * 2 + c;
            const int row = ch * 8 + srow;
            const int gu  = sun ^ (row & 7);
            gld_lds16(Kg  + ((size_t)bh * L_  + s0 + row) * HD_ + gu * 8, &Ks[bufi][ch * 512]);
            gld_lds16(Vtg + ((size_t)bh * HD_ + row) * L_  + s0 + gu * 8, &Vs[bufi][ch * 512]);
        }
    };

    stage(0, 0);
    __syncthreads();
    int buf = 0;
    for (int s0 = 0; s0 < L_; s0 += 64) {
        if (s0 + 64 < L_) stage(buf ^ 1, s0 + 64);

        u32 mlo[4], mhi[4];
#pragma unroll
        for (int r = 0; r < 4; ++r) {
            const int lrow = l0 + wave * 16 + ((lane >> 4) << 2) + r;
            const u64 m = mb[((size_t)b * L_ + lrow) * (L_ / 64) + (s0 >> 6)];
            mlo[r] = (u32)m; mhi[r] = (u32)(m >> 32);
        }
        float2 kk[4];
#pragma unroll
        for (int f = 0; f < 4; ++f)
            kk[f] = knrk[bh * L_ + s0 + (f << 4) + (lane & 15)];

        const ushort_t* Kb = Ks[buf];
        const ushort_t* Vb = Vs[buf];

        short8 bk_[4][2];
#pragma unroll
        for (int f = 0; f < 4; ++f)
#pragma unroll
            for (int ks = 0; ks < 2; ++ks)
                bk_[f][ks] = *(const short8*)&Kb[ra[f * 2 + ks]];
        f32x4 c[4];
#pragma unroll
        for (int f = 0; f < 4; ++f) {
            c[f] = vzero;
            c[f] = __builtin_amdgcn_mfma_f32_16x16x32_bf16(aq[0], bk_[f][0], c[f], 0, 0, 0);
            c[f] = __builtin_amdgcn_mfma_f32_16x16x32_bf16(aq[1], bk_[f][1], c[f], 0, 0, 0);
        }
        short8 bv_[4][2];
#pragma unroll
        for (int nf = 0; nf < 4; ++nf)
#pragma unroll
            for (int ks = 0; ks < 2; ++ks)
                bv_[nf][ks] = *(const short8*)&Vb[ra[nf * 2 + ks]];

        // slim score transform + P write
        ushort_t* Pw = &Ps[wave][0];
#pragma unroll
        for (int f = 0; f < 4; ++f) {
            const float knv = kk[f].x, rkv = kk[f].y;
            const int sh = ((f & 1) << 4) + (lane & 15);
#pragma unroll
            for (int r = 0; r < 4; ++r) {
                const float qnk = qn_row[r] + knv;
                const float rqk = rq_row[r] * rkv;
                const float arg = fmaxf(fmaf(fmaf(-2.f, c[f][r], qnk), rqk, 1.f), 1.f);
                const float sc  = pmh * __builtin_amdgcn_rcpf(arg);
                float p = fmaf(sc, fmaf(sc, fmaf(sc, 0.16666667f, 0.5f), 1.f), 1.f);
                const u32 bits = (f < 2) ? mlo[r] : mhi[r];
                p = ((bits >> sh) & 1) ? p : 0.f;
                rowsum[r] += p;
                Pw[pw[f * 4 + r]] = f2b_rne(p);
            }
        }

        // PV
#pragma unroll
        for (int ks = 0; ks < 2; ++ks) {
            const short8 ap = *(const short8*)&Pw[pr[ks]];
#pragma unroll
            for (int nf = 0; nf < 4; ++nf)
                oacc[nf] = __builtin_amdgcn_mfma_f32_16x16x32_bf16(ap, bv_[nf][ks], oacc[nf], 0, 0, 0);
        }
        __syncthreads();
        buf ^= 1;
    }

#pragma unroll
    for (int r = 0; r < 4; ++r) {
        rowsum[r] += __shfl_xor(rowsum[r], 1);
        rowsum[r] += __shfl_xor(rowsum[r], 2);
        rowsum[r] += __shfl_xor(rowsum[r], 4);
        rowsum[r] += __shfl_xor(rowsum[r], 8);
        rowsum[r] = __fdividef(1.f, rowsum[r]);
    }
#pragma unroll
    for (int nf = 0; nf < 4; ++nf) {
        const int d = (nf << 4) + (lane & 15);
#pragma unroll
        for (int r = 0; r < 4; ++r) {
            const int lrow = l0 + wave * 16 + ((lane >> 4) << 2) + r;
            ctx[((size_t)b * L_ + lrow) * D_ + (h << 6) + d] = f2b_rne(oacc[nf][r] * rowsum[r]);
        }
    }
}

// ---------------------------------------------------------------------------
extern "C" void kernel_launch(void* const* d_in, const int* in_sizes, int n_in,
                              void* d_out, int out_size, void* d_ws, size_t ws_size,
                              hipStream_t stream) {
    const float* hs     = (const float*)d_in[0];
    const int*   mask   = (const int*)  d_in[1];
    const float* Wq     = (const float*)d_in[2];
    const float* bq     = (const float*)d_in[3];
    const float* Wk     = (const float*)d_in[4];
    const float* bk     = (const float*)d_in[5];
    const float* Wv     = (const float*)d_in[6];
    const float* bv     = (const float*)d_in[7];
    const float* Wo     = (const float*)d_in[8];
    const float* bo     = (const float*)d_in[9];
    const float* omega  = (const float*)d_in[10];
    const float* theta0 = (const float*)d_in[11];
    const float* cK     = (const float*)d_in[12];
    float* out = (float*)d_out;

    char* ws = (char*)d_ws;
    ushort_t* hsb  = (ushort_t*)ws;  ws += (size_t)2097152 * 2;
    ushort_t* Wcb  = (ushort_t*)ws;  ws += (size_t)3145728 * 2;
    ushort_t* Wob  = (ushort_t*)ws;  ws += (size_t)1048576 * 2;
    ushort_t* Qb   = (ushort_t*)ws;  ws += (size_t)2097152 * 2;
    ushort_t* Kb   = (ushort_t*)ws;  ws += (size_t)2097152 * 2;
    ushort_t* Vtb  = (ushort_t*)ws;  ws += (size_t)2097152 * 2;
    ushort_t* ctxb = (ushort_t*)ws;  ws += (size_t)2097152 * 2;
    u64*      mbits= (u64*)ws;       ws += (size_t)32768 * 8;
    float2*   qnrq = (float2*)ws;    ws += (size_t)32768 * 8;
    float2*   knrk = (float2*)ws;    ws += (size_t)32768 * 8;
    float*    pmf  = (float*)ws;

    prep_kernel<<<14337, 256, 0, stream>>>(hs, Wq, Wk, Wv, Wo, mask,
                                           omega, theta0, cK,
                                           hsb, Wcb, Wob, mbits,
                                           out + (size_t)B_ * L_ * D_, pmf);

    mfma_gemm_qkv<<<dim3(24, 16), 256, 0, stream>>>(hsb, Wcb, bq, bk, bv,
                                                    Qb, Kb, Vtb, qnrq, knrk);

    attn_mfma_kernel<<<dim3(16, 32), 256, 0, stream>>>(Qb, Kb, Vtb, mbits, pmf,
                                                       qnrq, knrk, ctxb);

    mfma_gemm_out<<<dim3(16, 32), 256, 0, stream>>>(ctxb, Wob, bo, out);
}

// Round 6
// 187.839 us; speedup vs baseline: 3.1921x; 1.0104x over previous
//
#include <hip/hip_runtime.h>
#include <hip/hip_bf16.h>
#include <math.h>

#define B_  2
#define L_  1024
#define D_  1024
#define H_  16
#define HD_ 64

typedef __attribute__((ext_vector_type(8))) short short8;
typedef __attribute__((ext_vector_type(4))) float f32x4;
typedef unsigned int u32;
typedef unsigned long long u64;
typedef unsigned short ushort_t;

__device__ inline float b2f(short s) {
    union { float f; u32 i; } c; c.i = ((u32)(unsigned short)s) << 16; return c.f;
}
// manual bf16 RNE (no NaN path; inputs always finite here)
__device__ inline ushort_t f2b_rne(float f) {
    union { float f; u32 i; } c; c.f = f;
    return (ushort_t)((c.i + 0x7fffu + ((c.i >> 16) & 1u)) >> 16);
}
__device__ inline void gld_lds16(const void* g, void* l) {
    __builtin_amdgcn_global_load_lds((const __attribute__((address_space(1))) u32*)g,
                                     (__attribute__((address_space(3))) u32*)l, 16, 0, 0);
}

// ---------------------------------------------------------------------------
// prep: all fp32->bf16 casts + mask bit-pack + kuramoto in ONE launch
// ---------------------------------------------------------------------------
__global__ __launch_bounds__(256)
void prep_kernel(const float* __restrict__ hs, const float* __restrict__ Wq,
                 const float* __restrict__ Wk, const float* __restrict__ Wv,
                 const float* __restrict__ Wo, const int* __restrict__ mask,
                 const float* __restrict__ omega, const float* __restrict__ theta0,
                 const float* __restrict__ cK,
                 ushort_t* __restrict__ hsb, ushort_t* __restrict__ Wcb,
                 ushort_t* __restrict__ Wob, u64* __restrict__ bits,
                 float* __restrict__ out_tail, float* __restrict__ phase_mod) {
    const int blk = blockIdx.x, t = threadIdx.x;
    if (blk < 6144) {
        const float* src; ushort_t* dst; int idx;
        if (blk < 2048)      { src = hs; dst = hsb;           idx = blk * 256 + t; }
        else if (blk < 3072) { src = Wq; dst = Wcb;           idx = (blk - 2048) * 256 + t; }
        else if (blk < 4096) { src = Wk; dst = Wcb + 1048576; idx = (blk - 3072) * 256 + t; }
        else if (blk < 5120) { src = Wv; dst = Wcb + 2097152; idx = (blk - 4096) * 256 + t; }
        else                 { src = Wo; dst = Wob;           idx = (blk - 5120) * 256 + t; }
        float4 v = ((const float4*)src)[idx];
        ushort4 o;
        o.x = f2b_rne(v.x); o.y = f2b_rne(v.y); o.z = f2b_rne(v.z); o.w = f2b_rne(v.w);
        ((ushort4*)dst)[idx] = o;
    } else if (blk < 14336) {
        const int i = (blk - 6144) * 256 + t;
        const u64 bal = __ballot(mask[i] != 0);
        if ((t & 63) == 0) bits[i >> 6] = bal;
    } else {
        __shared__ float ph[H_];
        __shared__ float mc_s, ms_s;
        if (t < H_) {
            const float ti = theta0[t];
            float s = 0.f;
            for (int j = 0; j < H_; ++j) s += cK[t * H_ + j] * sinf(theta0[j] - ti);
            ph[t] = ti + 0.1f * (omega[t] + (1.0f / H_) * s);
        }
        __syncthreads();
        if (t == 0) {
            float mc = 0.f, ms = 0.f;
            for (int j = 0; j < H_; ++j) { mc += cosf(ph[j]); ms += sinf(ph[j]); }
            mc *= (1.0f / H_); ms *= (1.0f / H_);
            mc_s = mc; ms_s = ms;
            const float ord = sqrtf(mc * mc + ms * ms);
            out_tail[B_ * H_ + 0] = ord;
            out_tail[B_ * H_ + 1] = ord;
        }
        __syncthreads();
        if (t < H_) {
            const float p = ph[t];
            const float pmv = cosf(p) * mc_s + sinf(p) * ms_s;
            out_tail[t] = p;
            out_tail[H_ + t] = p;
            phase_mod[t] = pmv;
            phase_mod[H_ + t] = pmv;
        }
    }
}

// ---------------------------------------------------------------------------
// QKV GEMM: 128x128 tile, BK=32, 4 waves (2x2, 64x64/wave), dbuf LDS.
// Epilogue: Q/K head-layout bf16 + fused row-norms; V transposed bf16.
// ---------------------------------------------------------------------------
__global__ __launch_bounds__(256)
void mfma_gemm_qkv(const ushort_t* __restrict__ A, const ushort_t* __restrict__ W,
                   const float* __restrict__ b0, const float* __restrict__ b1,
                   const float* __restrict__ b2,
                   ushort_t* __restrict__ Qo, ushort_t* __restrict__ Ko,
                   ushort_t* __restrict__ Vto,
                   float2* __restrict__ qnrq, float2* __restrict__ knrk) {
    __shared__ ushort_t As[2][4096];
    __shared__ ushort_t Bs[2][4096];
    const int t = threadIdx.x, wave = t >> 6, lane = t & 63;
    const int wr = wave >> 1, wc = wave & 1;
    const int m0 = blockIdx.y * 128, n0g = blockIdx.x * 128;

    const f32x4 vzero = {0.f, 0.f, 0.f, 0.f};
    f32x4 acc[4][4];
#pragma unroll
    for (int i = 0; i < 4; ++i)
#pragma unroll
        for (int j = 0; j < 4; ++j) acc[i][j] = vzero;

    const int srow = lane >> 2, sun = lane & 3;

    auto stage = [&](int bufi, int k0) {
#pragma unroll
        for (int c = 0; c < 2; ++c) {
            const int ch  = wave * 2 + c;
            const int row = ch * 16 + srow;
            const int gu  = sun ^ ((row >> 1) & 3);
            gld_lds16(A + (size_t)(m0 + row) * 1024 + k0 + gu * 8, &As[bufi][ch * 512]);
            gld_lds16(W + (size_t)(n0g + row) * 1024 + k0 + gu * 8, &Bs[bufi][ch * 512]);
        }
    };

    stage(0, 0);
    __syncthreads();
    int buf = 0;
    for (int it = 0; it < 32; ++it) {
        if (it < 31) stage(buf ^ 1, (it + 1) << 5);
        short8 af[4], bf[4];
#pragma unroll
        for (int mf = 0; mf < 4; ++mf) {
            const int row = wr * 64 + mf * 16 + (lane & 15);
            const int pu  = (lane >> 4) ^ ((row >> 1) & 3);
            af[mf] = *(const short8*)&As[buf][row * 32 + pu * 8];
        }
#pragma unroll
        for (int nf = 0; nf < 4; ++nf) {
            const int row = wc * 64 + nf * 16 + (lane & 15);
            const int pu  = (lane >> 4) ^ ((row >> 1) & 3);
            bf[nf] = *(const short8*)&Bs[buf][row * 32 + pu * 8];
        }
        __builtin_amdgcn_s_setprio(1);
#pragma unroll
        for (int mf = 0; mf < 4; ++mf)
#pragma unroll
            for (int nf = 0; nf < 4; ++nf)
                acc[mf][nf] = __builtin_amdgcn_mfma_f32_16x16x32_bf16(
                    af[mf], bf[nf], acc[mf][nf], 0, 0, 0);
        __builtin_amdgcn_s_setprio(0);
        __syncthreads();
        buf ^= 1;
    }

    const int matsel = n0g >> 10, nb = n0g & 1023;
    const int h = (nb + wc * 64) >> 6;
    const float* bias_p = (matsel == 0) ? b0 : (matsel == 1) ? b1 : b2;
    float bias[4];
#pragma unroll
    for (int nf = 0; nf < 4; ++nf)
        bias[nf] = bias_p[nb + wc * 64 + nf * 16 + (lane & 15)];

#pragma unroll
    for (int mf = 0; mf < 4; ++mf) {
        const int mrow = m0 + wr * 64 + mf * 16 + ((lane >> 4) << 2);
        const int bidx = mrow >> 10, lb = mrow & 1023;
        const int bh = bidx * 16 + h;
        if (matsel < 2) {
            ushort_t* dst = (matsel == 0) ? Qo : Ko;
#pragma unroll
            for (int r = 0; r < 4; ++r) {
                float v0 = acc[mf][0][r] + bias[0];
                float v1 = acc[mf][1][r] + bias[1];
                float v2 = acc[mf][2][r] + bias[2];
                float v3 = acc[mf][3][r] + bias[3];
                float s = v0 * v0;
                s = fmaf(v1, v1, s); s = fmaf(v2, v2, s); s = fmaf(v3, v3, s);
                s += __shfl_xor(s, 1); s += __shfl_xor(s, 2);
                s += __shfl_xor(s, 4); s += __shfl_xor(s, 8);
                const size_t rbase = ((size_t)bh * L_ + lb + r) * HD_ + (lane & 15);
                dst[rbase]      = f2b_rne(v0);
                dst[rbase + 16] = f2b_rne(v1);
                dst[rbase + 32] = f2b_rne(v2);
                dst[rbase + 48] = f2b_rne(v3);
                if ((lane & 15) == 0) {
                    const float om = 1.f - fminf(s, 0.99f);
                    if (matsel == 0)
                        qnrq[bh * L_ + lb + r] = make_float2(s, __fdividef(2.f, om));
                    else
                        knrk[bh * L_ + lb + r] = make_float2(s, __fdividef(1.f, om));
                }
            }
        } else {
#pragma unroll
            for (int nf = 0; nf < 4; ++nf) {
                const int d = nf * 16 + (lane & 15);
                ushort4 o;
                o.x = f2b_rne(acc[mf][nf][0] + bias[nf]);
                o.y = f2b_rne(acc[mf][nf][1] + bias[nf]);
                o.z = f2b_rne(acc[mf][nf][2] + bias[nf]);
                o.w = f2b_rne(acc[mf][nf][3] + bias[nf]);
                *(ushort4*)&Vto[((size_t)bh * HD_ + d) * L_ + lb] = o;
            }
        }
    }
}

// ---------------------------------------------------------------------------
// Output projection GEMM: out = ctx @ Wo^T + bo, fp32 out. 64x64 tile, BK=32.
// ---------------------------------------------------------------------------
__global__ __launch_bounds__(256)
void mfma_gemm_out(const ushort_t* __restrict__ A, const ushort_t* __restrict__ W,
                   const float* __restrict__ b0, float* __restrict__ Fo) {
    __shared__ ushort_t As[2][2048];
    __shared__ ushort_t Bs[2][2048];
    const int t = threadIdx.x, wave = t >> 6, lane = t & 63;
    const int m0 = blockIdx.y * 64, n0g = blockIdx.x * 64;

    const f32x4 vzero = {0.f, 0.f, 0.f, 0.f};
    f32x4 acc[4];
#pragma unroll
    for (int j = 0; j < 4; ++j) acc[j] = vzero;

    const int srow = lane >> 2, sun = lane & 3;

    auto stage = [&](int bufi, int k0) {
        const int row = wave * 16 + srow;
        const int gu  = sun ^ ((row >> 1) & 3);
        gld_lds16(A + (size_t)(m0 + row) * 1024 + k0 + gu * 8, &As[bufi][wave * 512]);
        gld_lds16(W + (size_t)(n0g + row) * 1024 + k0 + gu * 8, &Bs[bufi][wave * 512]);
    };

    stage(0, 0);
    __syncthreads();
    int buf = 0;
    for (int it = 0; it < 32; ++it) {
        if (it < 31) stage(buf ^ 1, (it + 1) << 5);
        short8 af, bf[4];
        {
            const int row = wave * 16 + (lane & 15);
            const int pu  = (lane >> 4) ^ ((row >> 1) & 3);
            af = *(const short8*)&As[buf][row * 32 + pu * 8];
        }
#pragma unroll
        for (int nf = 0; nf < 4; ++nf) {
            const int row = nf * 16 + (lane & 15);
            const int pu  = (lane >> 4) ^ ((row >> 1) & 3);
            bf[nf] = *(const short8*)&Bs[buf][row * 32 + pu * 8];
        }
        __builtin_amdgcn_s_setprio(1);
#pragma unroll
        for (int nf = 0; nf < 4; ++nf)
            acc[nf] = __builtin_amdgcn_mfma_f32_16x16x32_bf16(af, bf[nf], acc[nf], 0, 0, 0);
        __builtin_amdgcn_s_setprio(0);
        __syncthreads();
        buf ^= 1;
    }

#pragma unroll
    for (int nf = 0; nf < 4; ++nf) {
        const int n = n0g + nf * 16 + (lane & 15);
        const float bias = b0[n];
        const int m_base = m0 + wave * 16 + ((lane >> 4) << 2);
#pragma unroll
        for (int r = 0; r < 4; ++r)
            Fo[(size_t)(m_base + r) * 1024 + n] = acc[nf][r] + bias;
    }
}

// ---------------------------------------------------------------------------
// MFMA flash attention, SPLIT-S: blockIdx.z selects half the s-range.
// Partial fp32 O + partial rowsums out (combined by combine_kernel).
// ---------------------------------------------------------------------------
__global__ __launch_bounds__(256)
void attn_mfma_kernel(const ushort_t* __restrict__ Qg,
                      const ushort_t* __restrict__ Kg,
                      const ushort_t* __restrict__ Vtg,
                      const u64* __restrict__ mb,
                      const float* __restrict__ pm_arr,
                      const float2* __restrict__ qnrq,
                      const float2* __restrict__ knrk,
                      float* __restrict__ Opart,   // [2][32][1024][64] fp32
                      float* __restrict__ Spart) { // [2][32][1024] fp32
    __shared__ ushort_t Ks[2][4096];
    __shared__ ushort_t Vs[2][4096];
    __shared__ ushort_t Ps[4][1024];
    const int bh = blockIdx.y, b = bh >> 4;
    const int l0 = blockIdx.x << 6;
    const int sp = blockIdx.z;
    const int s_beg = sp << 9, s_end = s_beg + 512;
    const int t = threadIdx.x, wave = t >> 6, lane = t & 63;
    const float pmh = 0.5f * pm_arr[bh];
    const f32x4 vzero = {0.f, 0.f, 0.f, 0.f};

    // Q fragments in registers
    short8 aq[2];
    {
        const int qrow = l0 + wave * 16 + (lane & 15);
        const size_t qb = ((size_t)bh * L_ + qrow) * HD_ + ((lane >> 4) << 3);
        aq[0] = *(const short8*)&Qg[qb];
        aq[1] = *(const short8*)&Qg[qb + 32];
    }
    float qn_row[4], rq_row[4];
#pragma unroll
    for (int r = 0; r < 4; ++r) {
        const float2 qv = qnrq[bh * L_ + l0 + wave * 16 + ((lane >> 4) << 2) + r];
        qn_row[r] = qv.x; rq_row[r] = qv.y;
    }

    // precomputed (s0-invariant) LDS elem offsets
    int ra[8];
#pragma unroll
    for (int f = 0; f < 4; ++f)
#pragma unroll
        for (int ks = 0; ks < 2; ++ks) {
            const int row = (f << 4) + (lane & 15);
            const int pu  = ((ks << 2) + (lane >> 4)) ^ (row & 7);
            ra[f * 2 + ks] = (row << 6) + (pu << 3);
        }
    int pw[16];
#pragma unroll
    for (int f = 0; f < 4; ++f)
#pragma unroll
        for (int r = 0; r < 4; ++r) {
            const int prow = ((lane >> 4) << 2) + r;
            const int colc = (f << 4) + (lane & 15);
            const int pu2  = (colc >> 3) ^ (prow & 7);
            pw[f * 4 + r] = (prow << 6) + (pu2 << 3) + (colc & 7);
        }
    int pr[2];
#pragma unroll
    for (int ks = 0; ks < 2; ++ks) {
        const int m  = lane & 15;
        const int pu = ((ks << 2) + (lane >> 4)) ^ (m & 7);
        pr[ks] = (m << 6) + (pu << 3);
    }

    f32x4 oacc[4];
#pragma unroll
    for (int nf = 0; nf < 4; ++nf) oacc[nf] = vzero;
    float rowsum[4] = {0.f, 0.f, 0.f, 0.f};

    const int srow = lane >> 3, sun = lane & 7;

    auto stage = [&](int bufi, int s0) {
#pragma unroll
        for (int c = 0; c < 2; ++c) {
            const int ch  = wave * 2 + c;
            const int row = ch * 8 + srow;
            const int gu  = sun ^ (row & 7);
            gld_lds16(Kg  + ((size_t)bh * L_  + s0 + row) * HD_ + gu * 8, &Ks[bufi][ch * 512]);
            gld_lds16(Vtg + ((size_t)bh * HD_ + row) * L_  + s0 + gu * 8, &Vs[bufi][ch * 512]);
        }
    };

    stage(0, s_beg);
    __syncthreads();
    int buf = 0;
    for (int s0 = s_beg; s0 < s_end; s0 += 64) {
        if (s0 + 64 < s_end) stage(buf ^ 1, s0 + 64);

        u32 mlo[4], mhi[4];
#pragma unroll
        for (int r = 0; r < 4; ++r) {
            const int lrow = l0 + wave * 16 + ((lane >> 4) << 2) + r;
            const u64 m = mb[((size_t)b * L_ + lrow) * (L_ / 64) + (s0 >> 6)];
            mlo[r] = (u32)m; mhi[r] = (u32)(m >> 32);
        }
        float2 kk[4];
#pragma unroll
        for (int f = 0; f < 4; ++f)
            kk[f] = knrk[bh * L_ + s0 + (f << 4) + (lane & 15)];

        const ushort_t* Kb = Ks[buf];
        const ushort_t* Vb = Vs[buf];

        short8 bk_[4][2];
#pragma unroll
        for (int f = 0; f < 4; ++f)
#pragma unroll
            for (int ks = 0; ks < 2; ++ks)
                bk_[f][ks] = *(const short8*)&Kb[ra[f * 2 + ks]];
        f32x4 c[4];
        __builtin_amdgcn_s_setprio(1);
#pragma unroll
        for (int f = 0; f < 4; ++f) {
            c[f] = vzero;
            c[f] = __builtin_amdgcn_mfma_f32_16x16x32_bf16(aq[0], bk_[f][0], c[f], 0, 0, 0);
            c[f] = __builtin_amdgcn_mfma_f32_16x16x32_bf16(aq[1], bk_[f][1], c[f], 0, 0, 0);
        }
        __builtin_amdgcn_s_setprio(0);
        short8 bv_[4][2];
#pragma unroll
        for (int nf = 0; nf < 4; ++nf)
#pragma unroll
            for (int ks = 0; ks < 2; ++ks)
                bv_[nf][ks] = *(const short8*)&Vb[ra[nf * 2 + ks]];

        // slim score transform + P write
        ushort_t* Pw = &Ps[wave][0];
#pragma unroll
        for (int f = 0; f < 4; ++f) {
            const float knv = kk[f].x, rkv = kk[f].y;
            const int sh = ((f & 1) << 4) + (lane & 15);
#pragma unroll
            for (int r = 0; r < 4; ++r) {
                const float qnk = qn_row[r] + knv;
                const float rqk = rq_row[r] * rkv;
                const float arg = fmaxf(fmaf(fmaf(-2.f, c[f][r], qnk), rqk, 1.f), 1.f);
                const float sc  = pmh * __builtin_amdgcn_rcpf(arg);
                float p = fmaf(sc, fmaf(sc, fmaf(sc, 0.16666667f, 0.5f), 1.f), 1.f);
                const u32 bits = (f < 2) ? mlo[r] : mhi[r];
                p = ((bits >> sh) & 1) ? p : 0.f;
                rowsum[r] += p;
                Pw[pw[f * 4 + r]] = f2b_rne(p);
            }
        }

        // PV
        __builtin_amdgcn_s_setprio(1);
#pragma unroll
        for (int ks = 0; ks < 2; ++ks) {
            const short8 ap = *(const short8*)&Pw[pr[ks]];
#pragma unroll
            for (int nf = 0; nf < 4; ++nf)
                oacc[nf] = __builtin_amdgcn_mfma_f32_16x16x32_bf16(ap, bv_[nf][ks], oacc[nf], 0, 0, 0);
        }
        __builtin_amdgcn_s_setprio(0);
        __syncthreads();
        buf ^= 1;
    }

    // partial rowsums (16-lane col-group reduce), one write per row
#pragma unroll
    for (int r = 0; r < 4; ++r) {
        rowsum[r] += __shfl_xor(rowsum[r], 1);
        rowsum[r] += __shfl_xor(rowsum[r], 2);
        rowsum[r] += __shfl_xor(rowsum[r], 4);
        rowsum[r] += __shfl_xor(rowsum[r], 8);
    }
    const int hi = lane >> 4;
    if ((lane & 15) == 0) {
#pragma unroll
        for (int r = 0; r < 4; ++r) {
            const int lrow = l0 + wave * 16 + (hi << 2) + r;
            Spart[((size_t)sp * 32 + bh) * L_ + lrow] = rowsum[r];
        }
    }
    // partial O (fp32)
#pragma unroll
    for (int nf = 0; nf < 4; ++nf) {
        const int d = (nf << 4) + (lane & 15);
#pragma unroll
        for (int r = 0; r < 4; ++r) {
            const int lrow = l0 + wave * 16 + (hi << 2) + r;
            Opart[(((size_t)sp * 32 + bh) * L_ + lrow) * HD_ + d] = oacc[nf][r];
        }
    }
}

// ---------------------------------------------------------------------------
// combine: ctx_bf16[b][l][h*64+d] = (O0+O1)/(S0+S1)
// ---------------------------------------------------------------------------
__global__ __launch_bounds__(256)
void combine_kernel(const float* __restrict__ Opart, const float* __restrict__ Spart,
                    ushort_t* __restrict__ ctx) {
    const int tid = blockIdx.x * 256 + threadIdx.x;     // 524288 threads
    const int e0  = tid << 2;                           // elem base in [bh][l][d]
    const int bh  = e0 >> 16;
    const int l   = (e0 >> 6) & 1023;
    const int d   = e0 & 63;
    const int rl  = bh * L_ + l;
    const float4 o0 = *(const float4*)&Opart[(size_t)rl * HD_ + d];
    const float4 o1 = *(const float4*)&Opart[(size_t)(rl + 32 * L_) * HD_ + d];
    const float inv = __fdividef(1.f, Spart[rl] + Spart[rl + 32 * L_]);
    ushort4 o;
    o.x = f2b_rne((o0.x + o1.x) * inv);
    o.y = f2b_rne((o0.y + o1.y) * inv);
    o.z = f2b_rne((o0.z + o1.z) * inv);
    o.w = f2b_rne((o0.w + o1.w) * inv);
    const int b = bh >> 4, h = bh & 15;
    *(ushort4*)&ctx[((size_t)b * L_ + l) * D_ + (h << 6) + d] = o;
}

// ---------------------------------------------------------------------------
extern "C" void kernel_launch(void* const* d_in, const int* in_sizes, int n_in,
                              void* d_out, int out_size, void* d_ws, size_t ws_size,
                              hipStream_t stream) {
    const float* hs     = (const float*)d_in[0];
    const int*   mask   = (const int*)  d_in[1];
    const float* Wq     = (const float*)d_in[2];
    const float* bq     = (const float*)d_in[3];
    const float* Wk     = (const float*)d_in[4];
    const float* bk     = (const float*)d_in[5];
    const float* Wv     = (const float*)d_in[6];
    const float* bv     = (const float*)d_in[7];
    const float* Wo     = (const float*)d_in[8];
    const float* bo     = (const float*)d_in[9];
    const float* omega  = (const float*)d_in[10];
    const float* theta0 = (const float*)d_in[11];
    const float* cK     = (const float*)d_in[12];
    float* out = (float*)d_out;

    char* ws = (char*)d_ws;
    ushort_t* hsb  = (ushort_t*)ws;  ws += (size_t)2097152 * 2;
    ushort_t* Wcb  = (ushort_t*)ws;  ws += (size_t)3145728 * 2;
    ushort_t* Wob  = (ushort_t*)ws;  ws += (size_t)1048576 * 2;
    ushort_t* Qb   = (ushort_t*)ws;  ws += (size_t)2097152 * 2;
    ushort_t* Kb   = (ushort_t*)ws;  ws += (size_t)2097152 * 2;
    ushort_t* Vtb  = (ushort_t*)ws;  ws += (size_t)2097152 * 2;
    ushort_t* ctxb = (ushort_t*)ws;  ws += (size_t)2097152 * 2;
    u64*      mbits= (u64*)ws;       ws += (size_t)32768 * 8;
    float2*   qnrq = (float2*)ws;    ws += (size_t)32768 * 8;
    float2*   knrk = (float2*)ws;    ws += (size_t)32768 * 8;
    float*    Opart= (float*)ws;     ws += (size_t)4194304 * 4;
    float*    Spart= (float*)ws;     ws += (size_t)65536 * 4;
    float*    pmf  = (float*)ws;

    prep_kernel<<<14337, 256, 0, stream>>>(hs, Wq, Wk, Wv, Wo, mask,
                                           omega, theta0, cK,
                                           hsb, Wcb, Wob, mbits,
                                           out + (size_t)B_ * L_ * D_, pmf);

    mfma_gemm_qkv<<<dim3(24, 16), 256, 0, stream>>>(hsb, Wcb, bq, bk, bv,
                                                    Qb, Kb, Vtb, qnrq, knrk);

    attn_mfma_kernel<<<dim3(16, 32, 2), 256, 0, stream>>>(Qb, Kb, Vtb, mbits, pmf,
                                                          qnrq, knrk, Opart, Spart);

    combine_kernel<<<2048, 256, 0, stream>>>(Opart, Spart, ctxb);

    mfma_gemm_out<<<dim3(16, 32), 256, 0, stream>>>(ctxb, Wob, bo, out);
}

// Round 7
// 179.173 us; speedup vs baseline: 3.3465x; 1.0484x over previous
//
#include <hip/hip_runtime.h>
#include <hip/hip_bf16.h>
#include <math.h>

#define B_  2
#define L_  1024
#define D_  1024
#define H_  16
#define HD_ 64

typedef __attribute__((ext_vector_type(8))) short short8;
typedef __attribute__((ext_vector_type(4))) float f32x4;
typedef unsigned int u32;
typedef unsigned long long u64;
typedef unsigned short ushort_t;

// manual bf16 RNE (no NaN path; inputs always finite here)
__device__ inline ushort_t f2b_rne(float f) {
    union { float f; u32 i; } c; c.f = f;
    return (ushort_t)((c.i + 0x7fffu + ((c.i >> 16) & 1u)) >> 16);
}
// truncating bf16 (for P: truncation bias cancels between numerator & rowsum)
__device__ inline ushort_t f2b_trunc(float f) {
    union { float f; u32 i; } c; c.f = f;
    return (ushort_t)(c.i >> 16);
}
__device__ inline void gld_lds16(const void* g, void* l) {
    __builtin_amdgcn_global_load_lds((const __attribute__((address_space(1))) u32*)g,
                                     (__attribute__((address_space(3))) u32*)l, 16, 0, 0);
}

// ---------------------------------------------------------------------------
// prep: all fp32->bf16 casts + mask bit-pack + kuramoto in ONE launch
// ---------------------------------------------------------------------------
__global__ __launch_bounds__(256)
void prep_kernel(const float* __restrict__ hs, const float* __restrict__ Wq,
                 const float* __restrict__ Wk, const float* __restrict__ Wv,
                 const float* __restrict__ Wo, const int* __restrict__ mask,
                 const float* __restrict__ omega, const float* __restrict__ theta0,
                 const float* __restrict__ cK,
                 ushort_t* __restrict__ hsb, ushort_t* __restrict__ Wcb,
                 ushort_t* __restrict__ Wob, u64* __restrict__ bits,
                 float* __restrict__ out_tail, float* __restrict__ phase_mod) {
    const int blk = blockIdx.x, t = threadIdx.x;
    if (blk < 6144) {
        const float* src; ushort_t* dst; int idx;
        if (blk < 2048)      { src = hs; dst = hsb;           idx = blk * 256 + t; }
        else if (blk < 3072) { src = Wq; dst = Wcb;           idx = (blk - 2048) * 256 + t; }
        else if (blk < 4096) { src = Wk; dst = Wcb + 1048576; idx = (blk - 3072) * 256 + t; }
        else if (blk < 5120) { src = Wv; dst = Wcb + 2097152; idx = (blk - 4096) * 256 + t; }
        else                 { src = Wo; dst = Wob;           idx = (blk - 5120) * 256 + t; }
        float4 v = ((const float4*)src)[idx];
        ushort4 o;
        o.x = f2b_rne(v.x); o.y = f2b_rne(v.y); o.z = f2b_rne(v.z); o.w = f2b_rne(v.w);
        ((ushort4*)dst)[idx] = o;
    } else if (blk < 14336) {
        const int i = (blk - 6144) * 256 + t;
        const u64 bal = __ballot(mask[i] != 0);
        if ((t & 63) == 0) bits[i >> 6] = bal;
    } else {
        __shared__ float ph[H_];
        __shared__ float mc_s, ms_s;
        if (t < H_) {
            const float ti = theta0[t];
            float s = 0.f;
            for (int j = 0; j < H_; ++j) s += cK[t * H_ + j] * sinf(theta0[j] - ti);
            ph[t] = ti + 0.1f * (omega[t] + (1.0f / H_) * s);
        }
        __syncthreads();
        if (t == 0) {
            float mc = 0.f, ms = 0.f;
            for (int j = 0; j < H_; ++j) { mc += cosf(ph[j]); ms += sinf(ph[j]); }
            mc *= (1.0f / H_); ms *= (1.0f / H_);
            mc_s = mc; ms_s = ms;
            const float ord = sqrtf(mc * mc + ms * ms);
            out_tail[B_ * H_ + 0] = ord;
            out_tail[B_ * H_ + 1] = ord;
        }
        __syncthreads();
        if (t < H_) {
            const float p = ph[t];
            const float pmv = cosf(p) * mc_s + sinf(p) * ms_s;
            out_tail[t] = p;
            out_tail[H_ + t] = p;
            phase_mod[t] = pmv;
            phase_mod[H_ + t] = pmv;
        }
    }
}

// ---------------------------------------------------------------------------
// QKV GEMM: 128x64 tile (768 blocks = 3/CU), BK=32, 4 waves M-stacked
// (32x64 per wave, 2x4 frags), dbuf LDS, 1 barrier per K-step.
// Epilogue: Q/K head-layout bf16 + fused row-norms; V transposed bf16.
// ---------------------------------------------------------------------------
__global__ __launch_bounds__(256)
void mfma_gemm_qkv(const ushort_t* __restrict__ A, const ushort_t* __restrict__ W,
                   const float* __restrict__ b0, const float* __restrict__ b1,
                   const float* __restrict__ b2,
                   ushort_t* __restrict__ Qo, ushort_t* __restrict__ Ko,
                   ushort_t* __restrict__ Vto,
                   float2* __restrict__ qnrq, float2* __restrict__ knrk) {
    __shared__ ushort_t As[2][4096];   // 128 rows x 32 cols
    __shared__ ushort_t Bs[2][2048];   // 64 rows x 32 cols
    const int t = threadIdx.x, wave = t >> 6, lane = t & 63;
    const int m0 = blockIdx.y * 128, n0g = blockIdx.x * 64;

    const f32x4 vzero = {0.f, 0.f, 0.f, 0.f};
    f32x4 acc[2][4];
#pragma unroll
    for (int i = 0; i < 2; ++i)
#pragma unroll
        for (int j = 0; j < 4; ++j) acc[i][j] = vzero;

    const int srow = lane >> 2, sun = lane & 3;   // 64B rows, 16B units

    auto stage = [&](int bufi, int k0) {
#pragma unroll
        for (int c = 0; c < 2; ++c) {
            const int ch  = wave * 2 + c;
            const int row = ch * 16 + srow;              // 0..127
            const int gu  = sun ^ ((row >> 1) & 3);
            gld_lds16(A + (size_t)(m0 + row) * 1024 + k0 + gu * 8, &As[bufi][ch * 512]);
        }
        const int row = wave * 16 + srow;                // 0..63
        const int gu  = sun ^ ((row >> 1) & 3);
        gld_lds16(W + (size_t)(n0g + row) * 1024 + k0 + gu * 8, &Bs[bufi][wave * 512]);
    };

    stage(0, 0);
    __syncthreads();
    int buf = 0;
    for (int it = 0; it < 32; ++it) {
        if (it < 31) stage(buf ^ 1, (it + 1) << 5);
        short8 af[2], bf[4];
#pragma unroll
        for (int mf = 0; mf < 2; ++mf) {
            const int row = wave * 32 + mf * 16 + (lane & 15);
            const int pu  = (lane >> 4) ^ ((row >> 1) & 3);
            af[mf] = *(const short8*)&As[buf][row * 32 + pu * 8];
        }
#pragma unroll
        for (int nf = 0; nf < 4; ++nf) {
            const int row = nf * 16 + (lane & 15);
            const int pu  = (lane >> 4) ^ ((row >> 1) & 3);
            bf[nf] = *(const short8*)&Bs[buf][row * 32 + pu * 8];
        }
        __builtin_amdgcn_s_setprio(1);
#pragma unroll
        for (int mf = 0; mf < 2; ++mf)
#pragma unroll
            for (int nf = 0; nf < 4; ++nf)
                acc[mf][nf] = __builtin_amdgcn_mfma_f32_16x16x32_bf16(
                    af[mf], bf[nf], acc[mf][nf], 0, 0, 0);
        __builtin_amdgcn_s_setprio(0);
        __syncthreads();
        buf ^= 1;
    }

    const int matsel = n0g >> 10, nb = n0g & 1023;
    const int h = nb >> 6;                       // one head per block
    const float* bias_p = (matsel == 0) ? b0 : (matsel == 1) ? b1 : b2;
    float bias[4];
#pragma unroll
    for (int nf = 0; nf < 4; ++nf)
        bias[nf] = bias_p[nb + nf * 16 + (lane & 15)];

#pragma unroll
    for (int mf = 0; mf < 2; ++mf) {
        const int mrow = m0 + wave * 32 + mf * 16 + ((lane >> 4) << 2);
        const int bidx = mrow >> 10, lb = mrow & 1023;
        const int bh = bidx * 16 + h;
        if (matsel < 2) {
            ushort_t* dst = (matsel == 0) ? Qo : Ko;
#pragma unroll
            for (int r = 0; r < 4; ++r) {
                float v0 = acc[mf][0][r] + bias[0];
                float v1 = acc[mf][1][r] + bias[1];
                float v2 = acc[mf][2][r] + bias[2];
                float v3 = acc[mf][3][r] + bias[3];
                float s = v0 * v0;
                s = fmaf(v1, v1, s); s = fmaf(v2, v2, s); s = fmaf(v3, v3, s);
                s += __shfl_xor(s, 1); s += __shfl_xor(s, 2);
                s += __shfl_xor(s, 4); s += __shfl_xor(s, 8);
                const size_t rbase = ((size_t)bh * L_ + lb + r) * HD_ + (lane & 15);
                dst[rbase]      = f2b_rne(v0);
                dst[rbase + 16] = f2b_rne(v1);
                dst[rbase + 32] = f2b_rne(v2);
                dst[rbase + 48] = f2b_rne(v3);
                if ((lane & 15) == 0) {
                    const float om = 1.f - fminf(s, 0.99f);
                    if (matsel == 0)
                        qnrq[bh * L_ + lb + r] = make_float2(s, __fdividef(2.f, om));
                    else
                        knrk[bh * L_ + lb + r] = make_float2(s, __fdividef(1.f, om));
                }
            }
        } else {
#pragma unroll
            for (int nf = 0; nf < 4; ++nf) {
                const int d = nf * 16 + (lane & 15);
                ushort4 o;
                o.x = f2b_rne(acc[mf][nf][0] + bias[nf]);
                o.y = f2b_rne(acc[mf][nf][1] + bias[nf]);
                o.z = f2b_rne(acc[mf][nf][2] + bias[nf]);
                o.w = f2b_rne(acc[mf][nf][3] + bias[nf]);
                *(ushort4*)&Vto[((size_t)bh * HD_ + d) * L_ + lb] = o;
            }
        }
    }
}

// ---------------------------------------------------------------------------
// Output projection GEMM: out = ctx @ Wo^T + bo, fp32 out. 64x64 tile,
// BK=64 (16 barriers instead of 32), 4 waves M-stacked, dbuf.
// ---------------------------------------------------------------------------
__global__ __launch_bounds__(256)
void mfma_gemm_out(const ushort_t* __restrict__ A, const ushort_t* __restrict__ W,
                   const float* __restrict__ b0, float* __restrict__ Fo) {
    __shared__ ushort_t As[2][4096];   // 64 rows x 64 cols
    __shared__ ushort_t Bs[2][4096];
    const int t = threadIdx.x, wave = t >> 6, lane = t & 63;
    const int m0 = blockIdx.y * 64, n0g = blockIdx.x * 64;

    const f32x4 vzero = {0.f, 0.f, 0.f, 0.f};
    f32x4 acc[4];
#pragma unroll
    for (int j = 0; j < 4; ++j) acc[j] = vzero;

    const int srow = lane >> 3, sun = lane & 7;   // 128B rows, 16B units

    auto stage = [&](int bufi, int k0) {
#pragma unroll
        for (int c = 0; c < 2; ++c) {
            const int ch  = wave * 2 + c;         // 0..7
            const int row = ch * 8 + srow;        // 0..63
            const int gu  = sun ^ (row & 7);
            gld_lds16(A + (size_t)(m0 + row) * 1024 + k0 + gu * 8, &As[bufi][ch * 512]);
            gld_lds16(W + (size_t)(n0g + row) * 1024 + k0 + gu * 8, &Bs[bufi][ch * 512]);
        }
    };

    stage(0, 0);
    __syncthreads();
    int buf = 0;
    for (int it = 0; it < 16; ++it) {
        if (it < 15) stage(buf ^ 1, (it + 1) << 6);
        short8 af[2], bf[4][2];
#pragma unroll
        for (int ks = 0; ks < 2; ++ks) {
            const int row = wave * 16 + (lane & 15);
            const int pu  = ((ks << 2) + (lane >> 4)) ^ (row & 7);
            af[ks] = *(const short8*)&As[buf][(row << 6) + (pu << 3)];
        }
#pragma unroll
        for (int nf = 0; nf < 4; ++nf) {
            const int row = nf * 16 + (lane & 15);
#pragma unroll
            for (int ks = 0; ks < 2; ++ks) {
                const int pu = ((ks << 2) + (lane >> 4)) ^ (row & 7);
                bf[nf][ks] = *(const short8*)&Bs[buf][(row << 6) + (pu << 3)];
            }
        }
        __builtin_amdgcn_s_setprio(1);
#pragma unroll
        for (int ks = 0; ks < 2; ++ks)
#pragma unroll
            for (int nf = 0; nf < 4; ++nf)
                acc[nf] = __builtin_amdgcn_mfma_f32_16x16x32_bf16(af[ks], bf[nf][ks], acc[nf], 0, 0, 0);
        __builtin_amdgcn_s_setprio(0);
        __syncthreads();
        buf ^= 1;
    }

#pragma unroll
    for (int nf = 0; nf < 4; ++nf) {
        const int n = n0g + nf * 16 + (lane & 15);
        const float bias = b0[n];
        const int m_base = m0 + wave * 16 + ((lane >> 4) << 2);
#pragma unroll
        for (int r = 0; r < 4; ++r)
            Fo[(size_t)(m_base + r) * 1024 + n] = acc[nf][r] + bias;
    }
}

// ---------------------------------------------------------------------------
// MFMA flash attention, SPLIT-S: blockIdx.z selects half the s-range.
// Slim transform: arg = 1 + diff*rq*rk (diff = ||q-k||^2 >= 0, no clamp
// needed); score = pmh/arg; p = 1 + sc + sc^2/2 (|sc| tiny: arg >= ~1e5).
// ---------------------------------------------------------------------------
__global__ __launch_bounds__(256)
void attn_mfma_kernel(const ushort_t* __restrict__ Qg,
                      const ushort_t* __restrict__ Kg,
                      const ushort_t* __restrict__ Vtg,
                      const u64* __restrict__ mb,
                      const float* __restrict__ pm_arr,
                      const float2* __restrict__ qnrq,
                      const float2* __restrict__ knrk,
                      float* __restrict__ Opart,   // [2][32][1024][64] fp32
                      float* __restrict__ Spart) { // [2][32][1024] fp32
    __shared__ ushort_t Ks[2][4096];
    __shared__ ushort_t Vs[2][4096];
    __shared__ ushort_t Ps[4][1024];
    const int bh = blockIdx.y, b = bh >> 4;
    const int l0 = blockIdx.x << 6;
    const int sp = blockIdx.z;
    const int s_beg = sp << 9, s_end = s_beg + 512;
    const int t = threadIdx.x, wave = t >> 6, lane = t & 63;
    const float pmh = 0.5f * pm_arr[bh];
    const f32x4 vzero = {0.f, 0.f, 0.f, 0.f};

    // Q fragments in registers
    short8 aq[2];
    {
        const int qrow = l0 + wave * 16 + (lane & 15);
        const size_t qb = ((size_t)bh * L_ + qrow) * HD_ + ((lane >> 4) << 3);
        aq[0] = *(const short8*)&Qg[qb];
        aq[1] = *(const short8*)&Qg[qb + 32];
    }
    float qn_row[4], rq_row[4];
#pragma unroll
    for (int r = 0; r < 4; ++r) {
        const float2 qv = qnrq[bh * L_ + l0 + wave * 16 + ((lane >> 4) << 2) + r];
        qn_row[r] = qv.x; rq_row[r] = qv.y;
    }

    // precomputed (s0-invariant) LDS elem offsets
    int ra[8];
#pragma unroll
    for (int f = 0; f < 4; ++f)
#pragma unroll
        for (int ks = 0; ks < 2; ++ks) {
            const int row = (f << 4) + (lane & 15);
            const int pu  = ((ks << 2) + (lane >> 4)) ^ (row & 7);
            ra[f * 2 + ks] = (row << 6) + (pu << 3);
        }
    int pw[16];
#pragma unroll
    for (int f = 0; f < 4; ++f)
#pragma unroll
        for (int r = 0; r < 4; ++r) {
            const int prow = ((lane >> 4) << 2) + r;
            const int colc = (f << 4) + (lane & 15);
            const int pu2  = (colc >> 3) ^ (prow & 7);
            pw[f * 4 + r] = (prow << 6) + (pu2 << 3) + (colc & 7);
        }
    int pr[2];
#pragma unroll
    for (int ks = 0; ks < 2; ++ks) {
        const int m  = lane & 15;
        const int pu = ((ks << 2) + (lane >> 4)) ^ (m & 7);
        pr[ks] = (m << 6) + (pu << 3);
    }

    f32x4 oacc[4];
#pragma unroll
    for (int nf = 0; nf < 4; ++nf) oacc[nf] = vzero;
    float rowsum[4] = {0.f, 0.f, 0.f, 0.f};

    const int srow = lane >> 3, sun = lane & 7;

    auto stage = [&](int bufi, int s0) {
#pragma unroll
        for (int c = 0; c < 2; ++c) {
            const int ch  = wave * 2 + c;
            const int row = ch * 8 + srow;
            const int gu  = sun ^ (row & 7);
            gld_lds16(Kg  + ((size_t)bh * L_  + s0 + row) * HD_ + gu * 8, &Ks[bufi][ch * 512]);
            gld_lds16(Vtg + ((size_t)bh * HD_ + row) * L_  + s0 + gu * 8, &Vs[bufi][ch * 512]);
        }
    };

    stage(0, s_beg);
    __syncthreads();
    int buf = 0;
    for (int s0 = s_beg; s0 < s_end; s0 += 64) {
        if (s0 + 64 < s_end) stage(buf ^ 1, s0 + 64);

        u32 mlo[4], mhi[4];
#pragma unroll
        for (int r = 0; r < 4; ++r) {
            const int lrow = l0 + wave * 16 + ((lane >> 4) << 2) + r;
            const u64 m = mb[((size_t)b * L_ + lrow) * (L_ / 64) + (s0 >> 6)];
            mlo[r] = (u32)m; mhi[r] = (u32)(m >> 32);
        }
        float2 kk[4];
#pragma unroll
        for (int f = 0; f < 4; ++f)
            kk[f] = knrk[bh * L_ + s0 + (f << 4) + (lane & 15)];

        const ushort_t* Kb = Ks[buf];
        const ushort_t* Vb = Vs[buf];

        short8 bk_[4][2];
#pragma unroll
        for (int f = 0; f < 4; ++f)
#pragma unroll
            for (int ks = 0; ks < 2; ++ks)
                bk_[f][ks] = *(const short8*)&Kb[ra[f * 2 + ks]];
        f32x4 c[4];
        __builtin_amdgcn_s_setprio(1);
#pragma unroll
        for (int f = 0; f < 4; ++f) {
            c[f] = vzero;
            c[f] = __builtin_amdgcn_mfma_f32_16x16x32_bf16(aq[0], bk_[f][0], c[f], 0, 0, 0);
            c[f] = __builtin_amdgcn_mfma_f32_16x16x32_bf16(aq[1], bk_[f][1], c[f], 0, 0, 0);
        }
        __builtin_amdgcn_s_setprio(0);
        short8 bv_[4][2];
#pragma unroll
        for (int nf = 0; nf < 4; ++nf)
#pragma unroll
            for (int ks = 0; ks < 2; ++ks)
                bv_[nf][ks] = *(const short8*)&Vb[ra[nf * 2 + ks]];

        // slim score transform + P write
        ushort_t* Pw = &Ps[wave][0];
#pragma unroll
        for (int f = 0; f < 4; ++f) {
            const float knv = kk[f].x, rkv = kk[f].y;
            const int sh = ((f & 1) << 4) + (lane & 15);
#pragma unroll
            for (int r = 0; r < 4; ++r) {
                const float qnk = qn_row[r] + knv;
                const float rqk = rq_row[r] * rkv;
                const float arg = fmaf(fmaf(-2.f, c[f][r], qnk), rqk, 1.f);
                const float sc  = pmh * __builtin_amdgcn_rcpf(arg);
                float p = fmaf(sc, fmaf(sc, 0.5f, 1.f), 1.f);
                const u32 bits = (f < 2) ? mlo[r] : mhi[r];
                p = ((bits >> sh) & 1) ? p : 0.f;
                rowsum[r] += p;
                Pw[pw[f * 4 + r]] = f2b_trunc(p);
            }
        }

        // PV
        __builtin_amdgcn_s_setprio(1);
#pragma unroll
        for (int ks = 0; ks < 2; ++ks) {
            const short8 ap = *(const short8*)&Pw[pr[ks]];
#pragma unroll
            for (int nf = 0; nf < 4; ++nf)
                oacc[nf] = __builtin_amdgcn_mfma_f32_16x16x32_bf16(ap, bv_[nf][ks], oacc[nf], 0, 0, 0);
        }
        __builtin_amdgcn_s_setprio(0);
        __syncthreads();
        buf ^= 1;
    }

    // partial rowsums (16-lane col-group reduce), one write per row
#pragma unroll
    for (int r = 0; r < 4; ++r) {
        rowsum[r] += __shfl_xor(rowsum[r], 1);
        rowsum[r] += __shfl_xor(rowsum[r], 2);
        rowsum[r] += __shfl_xor(rowsum[r], 4);
        rowsum[r] += __shfl_xor(rowsum[r], 8);
    }
    const int hi = lane >> 4;
    if ((lane & 15) == 0) {
#pragma unroll
        for (int r = 0; r < 4; ++r) {
            const int lrow = l0 + wave * 16 + (hi << 2) + r;
            Spart[((size_t)sp * 32 + bh) * L_ + lrow] = rowsum[r];
        }
    }
    // partial O (fp32)
#pragma unroll
    for (int nf = 0; nf < 4; ++nf) {
        const int d = (nf << 4) + (lane & 15);
#pragma unroll
        for (int r = 0; r < 4; ++r) {
            const int lrow = l0 + wave * 16 + (hi << 2) + r;
            Opart[(((size_t)sp * 32 + bh) * L_ + lrow) * HD_ + d] = oacc[nf][r];
        }
    }
}

// ---------------------------------------------------------------------------
// combine: ctx_bf16[b][l][h*64+d] = (O0+O1)/(S0+S1)
// ---------------------------------------------------------------------------
__global__ __launch_bounds__(256)
void combine_kernel(const float* __restrict__ Opart, const float* __restrict__ Spart,
                    ushort_t* __restrict__ ctx) {
    const int tid = blockIdx.x * 256 + threadIdx.x;     // 524288 threads
    const int e0  = tid << 2;                           // elem base in [bh][l][d]
    const int bh  = e0 >> 16;
    const int l   = (e0 >> 6) & 1023;
    const int d   = e0 & 63;
    const int rl  = bh * L_ + l;
    const float4 o0 = *(const float4*)&Opart[(size_t)rl * HD_ + d];
    const float4 o1 = *(const float4*)&Opart[(size_t)(rl + 32 * L_) * HD_ + d];
    const float inv = __fdividef(1.f, Spart[rl] + Spart[rl + 32 * L_]);
    ushort4 o;
    o.x = f2b_rne((o0.x + o1.x) * inv);
    o.y = f2b_rne((o0.y + o1.y) * inv);
    o.z = f2b_rne((o0.z + o1.z) * inv);
    o.w = f2b_rne((o0.w + o1.w) * inv);
    const int b = bh >> 4, h = bh & 15;
    *(ushort4*)&ctx[((size_t)b * L_ + l) * D_ + (h << 6) + d] = o;
}

// ---------------------------------------------------------------------------
extern "C" void kernel_launch(void* const* d_in, const int* in_sizes, int n_in,
                              void* d_out, int out_size, void* d_ws, size_t ws_size,
                              hipStream_t stream) {
    const float* hs     = (const float*)d_in[0];
    const int*   mask   = (const int*)  d_in[1];
    const float* Wq     = (const float*)d_in[2];
    const float* bq     = (const float*)d_in[3];
    const float* Wk     = (const float*)d_in[4];
    const float* bk     = (const float*)d_in[5];
    const float* Wv     = (const float*)d_in[6];
    const float* bv     = (const float*)d_in[7];
    const float* Wo     = (const float*)d_in[8];
    const float* bo     = (const float*)d_in[9];
    const float* omega  = (const float*)d_in[10];
    const float* theta0 = (const float*)d_in[11];
    const float* cK     = (const float*)d_in[12];
    float* out = (float*)d_out;

    char* ws = (char*)d_ws;
    ushort_t* hsb  = (ushort_t*)ws;  ws += (size_t)2097152 * 2;
    ushort_t* Wcb  = (ushort_t*)ws;  ws += (size_t)3145728 * 2;
    ushort_t* Wob  = (ushort_t*)ws;  ws += (size_t)1048576 * 2;
    ushort_t* Qb   = (ushort_t*)ws;  ws += (size_t)2097152 * 2;
    ushort_t* Kb   = (ushort_t*)ws;  ws += (size_t)2097152 * 2;
    ushort_t* Vtb  = (ushort_t*)ws;  ws += (size_t)2097152 * 2;
    ushort_t* ctxb = (ushort_t*)ws;  ws += (size_t)2097152 * 2;
    u64*      mbits= (u64*)ws;       ws += (size_t)32768 * 8;
    float2*   qnrq = (float2*)ws;    ws += (size_t)32768 * 8;
    float2*   knrk = (float2*)ws;    ws += (size_t)32768 * 8;
    float*    Opart= (float*)ws;     ws += (size_t)4194304 * 4;
    float*    Spart= (float*)ws;     ws += (size_t)65536 * 4;
    float*    pmf  = (float*)ws;

    prep_kernel<<<14337, 256, 0, stream>>>(hs, Wq, Wk, Wv, Wo, mask,
                                           omega, theta0, cK,
                                           hsb, Wcb, Wob, mbits,
                                           out + (size_t)B_ * L_ * D_, pmf);

    mfma_gemm_qkv<<<dim3(48, 16), 256, 0, stream>>>(hsb, Wcb, bq, bk, bv,
                                                    Qb, Kb, Vtb, qnrq, knrk);

    attn_mfma_kernel<<<dim3(16, 32, 2), 256, 0, stream>>>(Qb, Kb, Vtb, mbits, pmf,
                                                          qnrq, knrk, Opart, Spart);

    combine_kernel<<<2048, 256, 0, stream>>>(Opart, Spart, ctxb);

    mfma_gemm_out<<<dim3(16, 32), 256, 0, stream>>>(ctxb, Wob, bo, out);
}